// Round 3
// baseline (1091.216 us; speedup 1.0000x reference)
//
#include <hip/hip_runtime.h>

#define DEVINL __device__ __forceinline__

typedef __attribute__((ext_vector_type(8))) short bf8v;
typedef __attribute__((ext_vector_type(4))) float f4v;

DEVINL float b2f(unsigned short u){ union{unsigned int i; float f;} x; x.i = ((unsigned int)u)<<16; return x.f; }
DEVINL unsigned short f2b(float f){ union{float f; unsigned int i;} x; x.f = f; unsigned int r = x.i + 0x7FFFu + ((x.i>>16)&1u); return (unsigned short)(r>>16); }
DEVINL float sigf(float v){ return 1.f/(1.f + __expf(-v)); }
DEVINL void unpack8(const uint4 u, float* d){
  d[0]=b2f((unsigned short)(u.x)); d[1]=b2f((unsigned short)(u.x>>16));
  d[2]=b2f((unsigned short)(u.y)); d[3]=b2f((unsigned short)(u.y>>16));
  d[4]=b2f((unsigned short)(u.z)); d[5]=b2f((unsigned short)(u.z>>16));
  d[6]=b2f((unsigned short)(u.w)); d[7]=b2f((unsigned short)(u.w>>16));
}

// B=64 IMG=384 PS=16 DM=96 DS=16 DI=96 DT_RANK=6 NREP=4 NCLS=5 HP=24 N=576, M=36864
// ALL external I/O is FLOAT32 (per harness contract + reference dtypes).
// Internal GEMM operands are bf16 in workspace.

// ---------------- workspace layout (bytes; high-water ~71.2 MB) ----------------
#define WS_XLOG   ((size_t)0)            // bf16 28311552 el (k_blur -> k_patch)
#define WS_TOKRAW ((size_t)56623104)     // f32 3538944 el (k_patch -> k_ln<true>)
#define WS_VIS    ((size_t)70778880)     // f32 36864     [permanent]
#define WS_WGT    ((size_t)70926336)     // bf16 96*96
#define WS_WIT    ((size_t)70944768)     // bf16 192*96
#define WS_WXT    ((size_t)70981632)     // bf16 128*96
#define WS_WOT    ((size_t)71006208)     // bf16 96*96
#define WS_AMAT   ((size_t)71024640)     // f32 96*16
#define WS_WPE    ((size_t)71030784)     // bf16 96*768  -> end 71178240
// Phase B (inside dead xlog/tokraw region):
#define WS_TOK    ((size_t)0)            // f32 3538944 (residual stream)
#define WS_GATE   ((size_t)14155776)     // bf16 3538944
#define WS_DNB    ((size_t)21233664)     // bf16 (alias XSB; dnb dead before first conv)
#define WS_XSB    ((size_t)21233664)     // bf16 3538944
#define WS_HB     ((size_t)28311552)     // bf16 (alias Y2; hb dead before scan writes y2)
#define WS_Y2     ((size_t)28311552)     // bf16 3538944
#define WS_XIN    ((size_t)35389440)     // bf16 3538944
#define WS_ZSV    ((size_t)42467328)     // bf16 3538944
#define WS_DT     ((size_t)49545216)     // bf16 3538944 -> end 56623104
#define WS_BC     ((size_t)56623104)     // bf16 36864*32 -> end 58982400 (dead tokraw)

// ---------------- prep: bf16-ify weights (transposed), W_dt fold, A matrix ----------------
__global__ __launch_bounds__(256) void k_prep(
    const float* __restrict__ Wgate, const float* __restrict__ Win,
    const float* __restrict__ Wxproj, const float* __restrict__ Wdt,
    const float* __restrict__ Wout, const float* __restrict__ Alog,
    const float* __restrict__ Wpe,
    unsigned short* __restrict__ WgT, unsigned short* __restrict__ WiT,
    unsigned short* __restrict__ WxT, unsigned short* __restrict__ WoT,
    float* __restrict__ Amat, unsigned short* __restrict__ WpeB)
{
  int tid = threadIdx.x;
  for (int i = tid; i < 9216; i += 256){
    int n = i/96, k = i - n*96;
    WgT[n*96+k] = f2b(Wgate[k*96+n]);
    WoT[n*96+k] = f2b(Wout[k*96+n]);
  }
  for (int i = tid; i < 18432; i += 256){
    int n = i/96, k = i - n*96;
    WiT[n*96+k] = f2b(Win[k*192+n]);
  }
  for (int i = tid; i < 12288; i += 256){
    int n = i/96, k = i - n*96;
    if (n < 96){
      float s = 0.f;
      for (int r = 0; r < 6; ++r) s += Wxproj[k*38+r] * Wdt[r*96+n];
      WxT[n*96+k] = f2b(s);
    } else {
      WxT[n*96+k] = f2b(Wxproj[k*38 + 6 + (n-96)]);
    }
  }
  for (int i = tid; i < 1536; i += 256) Amat[i] = -__expf(Alog[i]);
  for (int i = tid; i < 73728; i += 256) WpeB[i] = f2b(Wpe[i]);  // (n, c, ph, pw) row-major
}

// ---------------- K1: 5x5 box blur + log1p diff -> xlog (bf16) ----------------
__global__ __launch_bounds__(256) void k_blur(const float* __restrict__ x,
                                              unsigned short* __restrict__ xlog)
{
  __shared__ float xt[20*384];
  __shared__ float ht[20*384];
  int bid = blockIdx.x;            // 64*3*24
  int tile = bid % 24; int bc = bid / 24; int c = bc % 3; int b = bc / 3;
  const float* xin = x + (size_t)(b*3 + c) * 147456;
  unsigned short* xout = xlog + (size_t)(b*3 + c) * 147456;
  int y0 = tile * 16;
  for (int idx = threadIdx.x; idx < 20*384; idx += 256){
    int r = y0 - 2 + idx/384; int col = idx % 384;
    float v = 0.f;
    if (r >= 0 && r < 384) v = xin[r*384 + col];
    xt[idx] = v;
  }
  __syncthreads();
  for (int u = threadIdx.x; u < 320; u += 256){
    int r = u / 16; int seg = u - (u/16)*16;
    int c0 = seg * 24;
    const float* row = xt + r*384;
    float* hrow = ht + r*384;
    float s = row[c0] + row[c0+1];
    if (c0 >= 1) s += row[c0-1];
    if (c0 >= 2) s += row[c0-2];
    for (int cc = c0; cc < c0+24; ++cc){
      float add = (cc+2 < 384) ? row[cc+2] : 0.f;
      s += add;
      hrow[cc] = s;
      float sub = (cc-2 >= 0) ? row[cc-2] : 0.f;
      s -= sub;
    }
  }
  __syncthreads();
  for (int col = threadIdx.x; col < 384; col += 256){
    float v = ht[0*384+col] + ht[1*384+col] + ht[2*384+col] + ht[3*384+col];
    for (int lr = 0; lr < 16; ++lr){
      v += ht[(lr+4)*384+col];
      float L = fmaxf(v * 0.04f, 0.f);
      float xv = fmaxf(xt[(lr+2)*384+col], 0.f);
      float res = __logf(1.f + xv) - __logf(1.f + L);
      xout[(y0+lr)*384 + col] = f2b(res);
      v -= ht[lr*384+col];
    }
  }
}

// ---------------- K2: patch embed (MFMA, im2col-free) -> tokens_raw f32 ----------------
__global__ __launch_bounds__(256) void k_patch(const unsigned short* __restrict__ xlog,
    const unsigned short* __restrict__ WpeB, const float* __restrict__ bpe,
    float* __restrict__ tokraw)
{
  int wid = threadIdx.x >> 6, lane = threadIdx.x & 63;
  int m0 = (blockIdx.x*4 + wid)*32;
  int l15 = lane & 15, q = lane >> 4;
  int ma0 = m0 + l15, ma1 = ma0 + 16;
  int b0 = ma0/576; int r0 = ma0 - b0*576; int hp0 = r0/24; int wp0 = r0 - hp0*24;
  int b1 = ma1/576; int r1 = ma1 - b1*576; int hp1 = r1/24; int wp1 = r1 - hp1*24;
  size_t base0 = (size_t)b0*442368 + (size_t)hp0*6144 + (size_t)wp0*16;
  size_t base1 = (size_t)b1*442368 + (size_t)hp1*6144 + (size_t)wp1*16;
  f4v acc[2][6];
  #pragma unroll
  for (int i=0;i<2;++i)
    #pragma unroll
    for (int j=0;j<6;++j)
      #pragma unroll
      for (int r=0;r<4;++r) acc[i][j][r] = 0.f;
  for (int ks = 0; ks < 24; ++ks){
    int k0 = ks*32 + q*8;
    int c  = k0 >> 8;
    int ph = (k0 >> 4) & 15;
    int pw = k0 & 15;
    size_t off = (size_t)c*147456 + (size_t)ph*384 + pw;
    bf8v a0 = *(const bf8v*)(xlog + base0 + off);
    bf8v a1 = *(const bf8v*)(xlog + base1 + off);
    #pragma unroll
    for (int nf = 0; nf < 6; ++nf){
      bf8v bb = *(const bf8v*)(WpeB + (size_t)(nf*16 + l15)*768 + k0);
      acc[0][nf] = __builtin_amdgcn_mfma_f32_16x16x32_bf16(a0, bb, acc[0][nf], 0, 0, 0);
      acc[1][nf] = __builtin_amdgcn_mfma_f32_16x16x32_bf16(a1, bb, acc[1][nf], 0, 0, 0);
    }
  }
  #pragma unroll
  for (int mf=0; mf<2; ++mf)
    #pragma unroll
    for (int nf=0; nf<6; ++nf)
      #pragma unroll
      for (int r=0; r<4; ++r){
        int m = m0 + mf*16 + q*4 + r;
        int n = nf*16 + l15;
        tokraw[(size_t)m*96 + n] = acc[mf][nf][r] + bpe[n];
      }
}

// ---------------- LayerNorm (+optional vis) ----------------
template<bool WITH_VIS>
__global__ __launch_bounds__(256) void k_ln(const float* __restrict__ in,
    const float* __restrict__ g, const float* __restrict__ bta,
    const float* __restrict__ Wvis, const float* __restrict__ bvis,
    float* __restrict__ outf, unsigned short* __restrict__ outb, float* __restrict__ vis)
{
  __shared__ float S[128*97];
  __shared__ float mu[128];
  __shared__ float rs[128];
  size_t base = (size_t)blockIdx.x * 12288;
  const float4* p = (const float4*)(in + base);
  for (int i = threadIdx.x; i < 3072; i += 256){
    float4 v = p[i];
    int e = i*4; int tok = e/96; int k = e - tok*96;
    float* dst = &S[tok*97 + k];
    dst[0]=v.x; dst[1]=v.y; dst[2]=v.z; dst[3]=v.w;
  }
  __syncthreads();
  if (threadIdx.x < 128){
    int tok = threadIdx.x;
    float sum=0.f, sq=0.f, vd=0.f;
    for (int k = 0; k < 96; ++k){
      float xv = S[tok*97+k];
      sum += xv; sq += xv*xv;
      if (WITH_VIS) vd += xv * Wvis[k];
    }
    float m = sum * (1.f/96.f);
    float var = sq * (1.f/96.f) - m*m;
    mu[tok] = m;
    rs[tok] = rsqrtf(fmaxf(var, 0.f) + 1e-5f);
    if (WITH_VIS) vis[(size_t)blockIdx.x*128 + tok] = sigf(vd + bvis[0]);
  }
  __syncthreads();
  for (int i = threadIdx.x; i < 12288; i += 256){
    int tok = i/96; int k = i - tok*96;
    float val = (S[tok*97+k] - mu[tok]) * rs[tok] * g[k] + bta[k];
    if (outf) outf[base + i] = val;
    outb[base + i] = f2b(val);
  }
}

// ---------------- generic token GEMM: (36864 x 96) bf16 @ BT(NO x 96) bf16 ----------------
template<int NF, class Epi>
__global__ __launch_bounds__(256) void tokgemm96(const unsigned short* __restrict__ A,
    const unsigned short* __restrict__ BT, Epi epi)
{
  int wid = threadIdx.x >> 6, lane = threadIdx.x & 63;
  int m0 = (blockIdx.x*4 + wid)*32;
  int l15 = lane & 15, q = lane >> 4;
  f4v acc[2][NF];
  #pragma unroll
  for (int i=0;i<2;++i)
    #pragma unroll
    for (int j=0;j<NF;++j)
      #pragma unroll
      for (int r=0;r<4;++r) acc[i][j][r] = 0.f;
  const bf8v* a0p = (const bf8v*)(A) + (size_t)(m0 + l15)*12 + q;
  const bf8v* a1p = a0p + 192;
  const bf8v* bp  = (const bf8v*)(BT) + (size_t)l15*12 + q;
  #pragma unroll
  for (int ks = 0; ks < 3; ++ks){
    bf8v a0 = a0p[ks*4];
    bf8v a1 = a1p[ks*4];
    #pragma unroll
    for (int nf = 0; nf < NF; ++nf){
      bf8v bb = bp[nf*192 + ks*4];
      acc[0][nf] = __builtin_amdgcn_mfma_f32_16x16x32_bf16(a0, bb, acc[0][nf], 0, 0, 0);
      acc[1][nf] = __builtin_amdgcn_mfma_f32_16x16x32_bf16(a1, bb, acc[1][nf], 0, 0, 0);
    }
  }
  #pragma unroll
  for (int mf=0; mf<2; ++mf)
    #pragma unroll
    for (int nf=0; nf<NF; ++nf)
      #pragma unroll
      for (int r=0; r<4; ++r)
        epi(m0 + mf*16 + q*4 + r, nf*16 + l15, acc[mf][nf][r]);
}

struct GateEpi {
  const float* bg; unsigned short* gate;
  __device__ void operator()(int m, int n, float v) const {
    gate[(size_t)m*96 + n] = f2b(sigf(v + bg[n]));
  }
};
struct WinEpi {
  const float* vis; unsigned short* xin; unsigned short* zsv;
  __device__ void operator()(int m, int n, float v) const {
    if (n < 96) xin[(size_t)m*96 + n] = f2b(v);
    else {
      float s = v * sigf(v);
      zsv[(size_t)m*96 + (n-96)] = f2b(s * vis[m]);
    }
  }
};
struct XfoldEpi {
  const float* bdt; unsigned short* dt; unsigned short* bc;
  __device__ void operator()(int m, int n, float v) const {
    if (n < 96){
      float x = v + bdt[n];
      float sp = (x > 20.f) ? x : __logf(1.f + __expf(x));
      dt[(size_t)m*96 + n] = f2b(sp);
    } else {
      bc[(size_t)m*32 + (n-96)] = f2b(v);
    }
  }
};
struct WoutEpi {
  const unsigned short* gate; float* tokens;
  __device__ void operator()(int m, int n, float v) const {
    size_t i = (size_t)m*96 + n;
    tokens[i] = tokens[i] + v * b2f(gate[i]);
  }
};

// ---------------- causal depthwise conv1d (k=3) + silu -> xsb (bf16) ----------------
__global__ __launch_bounds__(256) void k_conv(const unsigned short* __restrict__ xin,
    const float* __restrict__ cw, unsigned short* __restrict__ xsb)
{
  int gidx = blockIdx.x*256 + threadIdx.x;   // exact 3538944
  int m = gidx / 96; int d = gidx - m*96; int t = m % 576;
  float w0 = cw[d*3+0], w1 = cw[d*3+1], w2 = cw[d*3+2];
  float v = w2 * b2f(xin[gidx]);
  if (t >= 1) v += w1 * b2f(xin[gidx - 96]);
  if (t >= 2) v += w0 * b2f(xin[gidx - 192]);
  float s = v * sigf(v);
  xsb[gidx] = f2b(s);
}

// ---------------- selective scan: chunked 2-pass with in-LDS combine ----------------
// grid: 64 b x 6 dgroups; block: 384 = 24 chunks x 16 d
__global__ __launch_bounds__(384) void k_scan(const unsigned short* __restrict__ dt,
    const unsigned short* __restrict__ xsb, const unsigned short* __restrict__ bc,
    const unsigned short* __restrict__ zsv, const float* __restrict__ Amat,
    const float* __restrict__ Dw, unsigned short* __restrict__ y2)
{
  __shared__ float Ul[24*16*17];
  __shared__ float Sl[24*16];
  int b = blockIdx.x / 6; int dg = blockIdx.x - b*6;
  int tid = threadIdx.x;
  int c = tid >> 4; int dl = tid & 15; int d = dg*16 + dl;
  float As[16];
  #pragma unroll
  for (int s = 0; s < 16; s += 4){
    float4 t4 = *(const float4*)(Amat + d*16 + s);
    As[s]=t4.x; As[s+1]=t4.y; As[s+2]=t4.z; As[s+3]=t4.w;
  }
  float h[16];
  #pragma unroll
  for (int s=0;s<16;++s) h[s]=0.f;
  float sdt = 0.f;
  int tbase = b*576 + c*24;
  // pass 1: from zero state, accumulate U and sum(dt)
  for (int i = 0; i < 24; ++i){
    size_t m = (size_t)(tbase + i);
    float dtv = b2f(dt[m*96 + d]);
    float dtx = dtv * b2f(xsb[m*96 + d]);
    const uint4* bp = (const uint4*)(bc + m*32);
    float Bv[16];
    unpack8(bp[0], Bv); unpack8(bp[1], Bv+8);
    sdt += dtv;
    #pragma unroll
    for (int s=0;s<16;++s) h[s] = __expf(As[s]*dtv)*h[s] + dtx*Bv[s];
  }
  {
    int base = (c*16 + dl)*17;
    #pragma unroll
    for (int s=0;s<16;++s) Ul[base + s] = h[s];
    Sl[c*16 + dl] = sdt;
  }
  __syncthreads();
  // combine: serial over chunks; Ul[cc] becomes inclusive prefix state
  if (tid < 256){
    int dl2 = tid >> 4, s2 = tid & 15;
    float A2 = Amat[(dg*16 + dl2)*16 + s2];
    float hh = 0.f;
    for (int cc = 0; cc < 24; ++cc){
      float u = Ul[(cc*16 + dl2)*17 + s2];
      float ss = Sl[cc*16 + dl2];
      hh = __expf(A2*ss)*hh + u;
      Ul[(cc*16 + dl2)*17 + s2] = hh;
    }
  }
  __syncthreads();
  // pass 2: correct initial state, emit y fused with D*xs, silu(z)*vis
  if (c == 0){
    #pragma unroll
    for (int s=0;s<16;++s) h[s] = 0.f;
  } else {
    int base = ((c-1)*16 + dl)*17;
    #pragma unroll
    for (int s=0;s<16;++s) h[s] = Ul[base + s];
  }
  float Dd = Dw[d];
  for (int i = 0; i < 24; ++i){
    size_t m = (size_t)(tbase + i);
    float dtv = b2f(dt[m*96 + d]);
    float xv = b2f(xsb[m*96 + d]);
    float dtx = dtv * xv;
    const uint4* bp = (const uint4*)(bc + m*32);
    float Bv[16], Cv[16];
    unpack8(bp[0], Bv); unpack8(bp[1], Bv+8);
    unpack8(bp[2], Cv); unpack8(bp[3], Cv+8);
    float p0=0.f,p1=0.f,p2=0.f,p3=0.f;
    #pragma unroll
    for (int s=0;s<16;s+=4){
      h[s+0] = __expf(As[s+0]*dtv)*h[s+0] + dtx*Bv[s+0]; p0 += h[s+0]*Cv[s+0];
      h[s+1] = __expf(As[s+1]*dtv)*h[s+1] + dtx*Bv[s+1]; p1 += h[s+1]*Cv[s+1];
      h[s+2] = __expf(As[s+2]*dtv)*h[s+2] + dtx*Bv[s+2]; p2 += h[s+2]*Cv[s+2];
      h[s+3] = __expf(As[s+3]*dtv)*h[s+3] + dtx*Bv[s+3]; p3 += h[s+3]*Cv[s+3];
    }
    float y = (p0+p1) + (p2+p3);
    float yv = (y + Dd*xv) * b2f(zsv[m*96 + d]);
    y2[m*96 + d] = f2b(yv);
  }
}

// ---------------- head: depthwise 3x3 + BN + silu + linear heads ----------------
__global__ __launch_bounds__(256) void k_head(const float* __restrict__ tokens,
    const float* __restrict__ hdw, const float* __restrict__ bng,
    const float* __restrict__ bnb, const float* __restrict__ bnm,
    const float* __restrict__ bnv, const float* __restrict__ Wheat,
    const float* __restrict__ bheat, const float* __restrict__ Woff,
    const float* __restrict__ boff, const float* __restrict__ Wsize,
    const float* __restrict__ bsize, float* __restrict__ out)
{
  __shared__ float ft[3*2304];
  __shared__ float act[2304];
  int b = blockIdx.x / 24; int h = blockIdx.x - b*24;
  for (int i = threadIdx.x; i < 3*2304; i += 256){
    int rr = i / 2304; int j = i - rr*2304;
    int hh = h + rr - 1;
    float v = 0.f;
    if (hh >= 0 && hh < 24) v = tokens[((size_t)b*576 + hh*24)*96 + j];
    ft[rr*2304 + j] = v;
  }
  __syncthreads();
  for (int i = threadIdx.x; i < 2304; i += 256){
    int w = i / 96; int cc = i - w*96;
    float g = 0.f;
    #pragma unroll
    for (int dh = 0; dh < 3; ++dh){
      #pragma unroll
      for (int dw = 0; dw < 3; ++dw){
        int ww = w + dw - 1;
        if (ww >= 0 && ww < 24) g += ft[dh*2304 + ww*96 + cc] * hdw[cc*9 + dh*3 + dw];
      }
    }
    float gn = (g - bnm[cc]) * rsqrtf(bnv[cc] + 1e-5f);
    float a = gn * bng[cc] + bnb[cc];
    act[i] = a * sigf(a);
  }
  __syncthreads();
  int tid = threadIdx.x;
  if (tid < 120){
    int o = tid / 24; int w = tid - o*24;
    float s = 0.f;
    for (int cc = 0; cc < 96; ++cc) s += act[w*96 + cc] * Wheat[o*96 + cc];
    s += bheat[o];
    out[(size_t)b*2880 + o*576 + h*24 + w] = s;
  } else if (tid >= 128 && tid < 224){
    int idx = tid - 128; int o2 = idx / 24; int w = idx - o2*24;
    const float* W = (o2 < 2) ? Woff : Wsize;
    int o = o2 & 1;
    float s = 0.f;
    for (int cc = 0; cc < 96; ++cc) s += ft[2304 + w*96 + cc] * W[o*96 + cc];
    s += ((o2 < 2) ? boff : bsize)[o];
    size_t baseo = (o2 < 2) ? (size_t)184320 : (size_t)258048;
    out[baseo + (size_t)b*1152 + o*576 + h*24 + w] = s;
  }
}

// ---------------- host ----------------
extern "C" void kernel_launch(void* const* d_in, const int* in_sizes, int n_in,
                              void* d_out, int out_size, void* d_ws, size_t ws_size,
                              hipStream_t stream)
{
  (void)in_sizes; (void)n_in; (void)out_size; (void)ws_size;
  const float* x      = (const float*)d_in[0];
  const float* Wpe    = (const float*)d_in[1];
  const float* bpe    = (const float*)d_in[2];
  const float* Wvis   = (const float*)d_in[3];
  const float* bvis   = (const float*)d_in[4];
  const float* dng    = (const float*)d_in[5];
  const float* dnb    = (const float*)d_in[6];
  const float* Wgate  = (const float*)d_in[7];
  const float* bgate  = (const float*)d_in[8];
  const float* lng    = (const float*)d_in[9];
  const float* lnb    = (const float*)d_in[10];
  const float* Win    = (const float*)d_in[11];
  const float* convw  = (const float*)d_in[12];
  const float* Wxproj = (const float*)d_in[13];
  const float* Wdt    = (const float*)d_in[14];
  const float* bdt    = (const float*)d_in[15];
  const float* Alog   = (const float*)d_in[16];
  const float* Dw     = (const float*)d_in[17];
  const float* Wout   = (const float*)d_in[18];
  const float* hddw   = (const float*)d_in[19];
  const float* bng    = (const float*)d_in[20];
  const float* bnb    = (const float*)d_in[21];
  const float* bnm    = (const float*)d_in[22];
  const float* bnv    = (const float*)d_in[23];
  const float* Wheat  = (const float*)d_in[24];
  const float* bheat  = (const float*)d_in[25];
  const float* Woff   = (const float*)d_in[26];
  const float* boff   = (const float*)d_in[27];
  const float* Wsize  = (const float*)d_in[28];
  const float* bsize  = (const float*)d_in[29];
  float* out = (float*)d_out;

  char* ws = (char*)d_ws;
  unsigned short* xlog  = (unsigned short*)(ws + WS_XLOG);
  float*          tokraw= (float*)(ws + WS_TOKRAW);
  float*          vis   = (float*)(ws + WS_VIS);
  unsigned short* WgT   = (unsigned short*)(ws + WS_WGT);
  unsigned short* WiT   = (unsigned short*)(ws + WS_WIT);
  unsigned short* WxT   = (unsigned short*)(ws + WS_WXT);
  unsigned short* WoT   = (unsigned short*)(ws + WS_WOT);
  float*          Amat  = (float*)(ws + WS_AMAT);
  unsigned short* WpeB  = (unsigned short*)(ws + WS_WPE);
  float*          tok   = (float*)(ws + WS_TOK);
  unsigned short* gate  = (unsigned short*)(ws + WS_GATE);
  unsigned short* dnbf  = (unsigned short*)(ws + WS_DNB);
  unsigned short* xsb   = (unsigned short*)(ws + WS_XSB);
  unsigned short* hb    = (unsigned short*)(ws + WS_HB);
  unsigned short* y2    = (unsigned short*)(ws + WS_Y2);
  unsigned short* xinb  = (unsigned short*)(ws + WS_XIN);
  unsigned short* zsvb  = (unsigned short*)(ws + WS_ZSV);
  unsigned short* dtb   = (unsigned short*)(ws + WS_DT);
  unsigned short* bcb   = (unsigned short*)(ws + WS_BC);

  k_prep<<<1, 256, 0, stream>>>(Wgate, Win, Wxproj, Wdt, Wout, Alog, Wpe,
                                WgT, WiT, WxT, WoT, Amat, WpeB);
  k_blur<<<4608, 256, 0, stream>>>(x, xlog);
  k_patch<<<288, 256, 0, stream>>>(xlog, WpeB, bpe, tokraw);
  k_ln<true><<<288, 256, 0, stream>>>(tokraw, dng, dnb, Wvis, bvis, tok, dnbf, vis);
  tokgemm96<6, GateEpi><<<288, 256, 0, stream>>>(dnbf, WgT, GateEpi{bgate, gate});

  for (int rep = 0; rep < 4; ++rep){
    k_ln<false><<<288, 256, 0, stream>>>(tok, lng, lnb, nullptr, nullptr, nullptr, hb, nullptr);
    tokgemm96<12, WinEpi><<<288, 256, 0, stream>>>(hb, WiT, WinEpi{vis, xinb, zsvb});
    k_conv<<<13824, 256, 0, stream>>>(xinb, convw, xsb);
    tokgemm96<8, XfoldEpi><<<288, 256, 0, stream>>>(xsb, WxT, XfoldEpi{bdt, dtb, bcb});
    k_scan<<<384, 384, 0, stream>>>(dtb, xsb, bcb, zsvb, Amat, Dw, y2);
    tokgemm96<6, WoutEpi><<<288, 256, 0, stream>>>(y2, WoT, WoutEpi{gate, tok});
  }

  k_head<<<1536, 256, 0, stream>>>(tok, hddw, bng, bnb, bnm, bnv,
                                   Wheat, bheat, Woff, boff, Wsize, bsize, out);
}

// Round 4
// 998.607 us; speedup vs baseline: 1.0927x; 1.0927x over previous
//
#include <hip/hip_runtime.h>

#define DEVINL __device__ __forceinline__

typedef __attribute__((ext_vector_type(8))) short bf8v;
typedef __attribute__((ext_vector_type(4))) float f4v;

DEVINL float b2f(unsigned short u){ union{unsigned int i; float f;} x; x.i = ((unsigned int)u)<<16; return x.f; }
DEVINL unsigned short f2b(float f){ union{float f; unsigned int i;} x; x.f = f; unsigned int r = x.i + 0x7FFFu + ((x.i>>16)&1u); return (unsigned short)(r>>16); }
DEVINL float sigf(float v){ return 1.f/(1.f + __expf(-v)); }
DEVINL void unpack8(const uint4 u, float* d){
  d[0]=b2f((unsigned short)(u.x)); d[1]=b2f((unsigned short)(u.x>>16));
  d[2]=b2f((unsigned short)(u.y)); d[3]=b2f((unsigned short)(u.y>>16));
  d[4]=b2f((unsigned short)(u.z)); d[5]=b2f((unsigned short)(u.z>>16));
  d[6]=b2f((unsigned short)(u.w)); d[7]=b2f((unsigned short)(u.w>>16));
}

// B=64 IMG=384 PS=16 DM=96 DS=16 DI=96 DT_RANK=6 NREP=4 NCLS=5 HP=24 N=576, M=36864
// External I/O: FLOAT32. Internal GEMM operands: bf16 in workspace.

// ---------------- workspace layout (bytes; high-water ~71.2 MB) ----------------
#define WS_XLOG   ((size_t)0)            // bf16 28311552 el (k_blur -> k_patch)
#define WS_TOKRAW ((size_t)56623104)     // f32 3538944 el (k_patch -> k_ln<true>)
#define WS_VIS    ((size_t)70778880)     // f32 36864     [permanent]
#define WS_WGT    ((size_t)70926336)     // bf16 96*96
#define WS_WIT    ((size_t)70944768)     // bf16 192*96
#define WS_WXT    ((size_t)70981632)     // bf16 128*96
#define WS_WOT    ((size_t)71006208)     // bf16 96*96
#define WS_AMAT   ((size_t)71024640)     // f32 96*16
#define WS_WPE    ((size_t)71030784)     // bf16 96*768  -> end 71178240
// Phase B (inside dead xlog/tokraw region):
#define WS_TOK    ((size_t)0)            // f32 3538944 (residual stream)
#define WS_GATE   ((size_t)14155776)     // bf16 3538944
#define WS_DNB    ((size_t)21233664)     // bf16 (alias XSB; dnb dead before first conv)
#define WS_XSB    ((size_t)21233664)     // bf16 3538944
#define WS_HB     ((size_t)28311552)     // bf16 (alias Y2; hb dead before scan writes y2)
#define WS_Y2     ((size_t)28311552)     // bf16 3538944
#define WS_XIN    ((size_t)35389440)     // bf16 3538944
#define WS_ZSV    ((size_t)42467328)     // bf16 3538944
#define WS_DT     ((size_t)49545216)     // bf16 3538944 -> end 56623104
#define WS_BC     ((size_t)56623104)     // bf16 36864*32 -> end 58982400 (dead tokraw)

// ---------------- prep: bf16-ify weights (transposed), W_dt fold, A matrix ----------------
__global__ __launch_bounds__(256) void k_prep(
    const float* __restrict__ Wgate, const float* __restrict__ Win,
    const float* __restrict__ Wxproj, const float* __restrict__ Wdt,
    const float* __restrict__ Wout, const float* __restrict__ Alog,
    const float* __restrict__ Wpe,
    unsigned short* __restrict__ WgT, unsigned short* __restrict__ WiT,
    unsigned short* __restrict__ WxT, unsigned short* __restrict__ WoT,
    float* __restrict__ Amat, unsigned short* __restrict__ WpeB)
{
  int tid = threadIdx.x;
  for (int i = tid; i < 9216; i += 256){
    int n = i/96, k = i - n*96;
    WgT[n*96+k] = f2b(Wgate[k*96+n]);
    WoT[n*96+k] = f2b(Wout[k*96+n]);
  }
  for (int i = tid; i < 18432; i += 256){
    int n = i/96, k = i - n*96;
    WiT[n*96+k] = f2b(Win[k*192+n]);
  }
  for (int i = tid; i < 12288; i += 256){
    int n = i/96, k = i - n*96;
    if (n < 96){
      float s = 0.f;
      for (int r = 0; r < 6; ++r) s += Wxproj[k*38+r] * Wdt[r*96+n];
      WxT[n*96+k] = f2b(s);
    } else {
      WxT[n*96+k] = f2b(Wxproj[k*38 + 6 + (n-96)]);
    }
  }
  for (int i = tid; i < 1536; i += 256) Amat[i] = -__expf(Alog[i]);
  for (int i = tid; i < 73728; i += 256) WpeB[i] = f2b(Wpe[i]);  // (n, c, ph, pw) row-major
}

// ---------------- K1: 5x5 box blur + log1p diff -> xlog (bf16) ----------------
// Redesigned: vertical-sum phase + horizontal-sum phase, fully parallel,
// float4 LDS ops, conflict-free (lane-consecutive addresses within rows).
__global__ __launch_bounds__(256) void k_blur(const float* __restrict__ x,
                                              unsigned short* __restrict__ xlog)
{
  __shared__ float xt[20*384];     // raw rows y0-2 .. y0+17
  __shared__ float vt[16*392];     // vertical 5-sums, padded 4 zeros each side
  int bid = blockIdx.x;            // 64*3*24
  int tile = bid % 24; int bc = bid / 24; int c = bc % 3; int b = bc / 3;
  const float* xin = x + (size_t)(b*3 + c) * 147456;
  unsigned short* xout = xlog + (size_t)(b*3 + c) * 147456;
  int y0 = tile * 16;
  int tid = threadIdx.x;

  // phase 1: stage 20 rows (zero-filled outside image) as float4
  #pragma unroll
  for (int k = 0; k < 8; ++k){           // 8*240=1920 float4 units? use 1920 = 256*7.5 -> loop 8 with guard
    int idx = tid + k*256;
    if (idx < 1920){
      int r = idx / 96; int c4 = idx - r*96;
      int gy = y0 - 2 + r;
      float4 v = make_float4(0.f,0.f,0.f,0.f);
      if (gy >= 0 && gy < 384) v = *(const float4*)(xin + gy*384 + c4*4);
      *(float4*)(xt + r*384 + c4*4) = v;
    }
  }
  // zero vt side pads: 16 rows * 8 floats
  if (tid < 128){
    int r = tid >> 3; int j = tid & 7;
    vt[r*392 + ((j < 4) ? j : (384 + j))] = 0.f;
  }
  __syncthreads();

  // phase 2: vertical 5-sums. 1536 units = (r=0..15, c4=0..95), 6 per thread.
  #pragma unroll
  for (int k = 0; k < 6; ++k){
    int unit = tid + k*256;
    int r = unit / 96; int c4 = unit - r*96;
    const float* base = xt + r*384 + c4*4;
    float4 s0 = *(const float4*)(base);
    float4 s1 = *(const float4*)(base + 384);
    float4 s2 = *(const float4*)(base + 768);
    float4 s3 = *(const float4*)(base + 1152);
    float4 s4 = *(const float4*)(base + 1536);
    float4 s;
    s.x = s0.x+s1.x+s2.x+s3.x+s4.x;
    s.y = s0.y+s1.y+s2.y+s3.y+s4.y;
    s.z = s0.z+s1.z+s2.z+s3.z+s4.z;
    s.w = s0.w+s1.w+s2.w+s3.w+s4.w;
    *(float4*)(vt + r*392 + 4 + c4*4) = s;
  }
  __syncthreads();

  // phase 3: horizontal 5-sums + log-diff + bf16 store. Same 1536-unit mapping.
  #pragma unroll
  for (int k = 0; k < 6; ++k){
    int unit = tid + k*256;
    int r = unit / 96; int c4 = unit - r*96;
    int base = r*392 + 4 + c4*4;
    float f[12];
    *(float4*)(f)   = *(const float4*)(vt + base - 4);
    *(float4*)(f+4) = *(const float4*)(vt + base);
    *(float4*)(f+8) = *(const float4*)(vt + base + 4);
    float4 xraw = *(const float4*)(xt + (r+2)*384 + c4*4);
    const float* xr = &xraw.x;
    ushort4 o;
    unsigned short* op = &o.x;
    #pragma unroll
    for (int j = 0; j < 4; ++j){
      float s = f[2+j] + f[3+j] + f[4+j] + f[5+j] + f[6+j];
      float L = fmaxf(s * 0.04f, 0.f);
      float xv = fmaxf(xr[j], 0.f);
      op[j] = f2b(__logf(1.f + xv) - __logf(1.f + L));
    }
    *(ushort4*)(xout + (y0+r)*384 + c4*4) = o;
  }
}

// ---------------- K2: patch embed (MFMA, im2col-free) -> tokens_raw f32 ----------------
__global__ __launch_bounds__(256) void k_patch(const unsigned short* __restrict__ xlog,
    const unsigned short* __restrict__ WpeB, const float* __restrict__ bpe,
    float* __restrict__ tokraw)
{
  int wid = threadIdx.x >> 6, lane = threadIdx.x & 63;
  int m0 = (blockIdx.x*4 + wid)*32;
  int l15 = lane & 15, q = lane >> 4;
  int ma0 = m0 + l15, ma1 = ma0 + 16;
  int b0 = ma0/576; int r0 = ma0 - b0*576; int hp0 = r0/24; int wp0 = r0 - hp0*24;
  int b1 = ma1/576; int r1 = ma1 - b1*576; int hp1 = r1/24; int wp1 = r1 - hp1*24;
  size_t base0 = (size_t)b0*442368 + (size_t)hp0*6144 + (size_t)wp0*16;
  size_t base1 = (size_t)b1*442368 + (size_t)hp1*6144 + (size_t)wp1*16;
  f4v acc[2][6];
  #pragma unroll
  for (int i=0;i<2;++i)
    #pragma unroll
    for (int j=0;j<6;++j)
      #pragma unroll
      for (int r=0;r<4;++r) acc[i][j][r] = 0.f;
  for (int ks = 0; ks < 24; ++ks){
    int k0 = ks*32 + q*8;
    int c  = k0 >> 8;
    int ph = (k0 >> 4) & 15;
    int pw = k0 & 15;
    size_t off = (size_t)c*147456 + (size_t)ph*384 + pw;
    bf8v a0 = *(const bf8v*)(xlog + base0 + off);
    bf8v a1 = *(const bf8v*)(xlog + base1 + off);
    #pragma unroll
    for (int nf = 0; nf < 6; ++nf){
      bf8v bb = *(const bf8v*)(WpeB + (size_t)(nf*16 + l15)*768 + k0);
      acc[0][nf] = __builtin_amdgcn_mfma_f32_16x16x32_bf16(a0, bb, acc[0][nf], 0, 0, 0);
      acc[1][nf] = __builtin_amdgcn_mfma_f32_16x16x32_bf16(a1, bb, acc[1][nf], 0, 0, 0);
    }
  }
  #pragma unroll
  for (int mf=0; mf<2; ++mf)
    #pragma unroll
    for (int nf=0; nf<6; ++nf)
      #pragma unroll
      for (int r=0; r<4; ++r){
        int m = m0 + mf*16 + q*4 + r;
        int n = nf*16 + l15;
        tokraw[(size_t)m*96 + n] = acc[mf][nf][r] + bpe[n];
      }
}

// ---------------- LayerNorm (+optional vis) ----------------
template<bool WITH_VIS>
__global__ __launch_bounds__(256) void k_ln(const float* __restrict__ in,
    const float* __restrict__ g, const float* __restrict__ bta,
    const float* __restrict__ Wvis, const float* __restrict__ bvis,
    float* __restrict__ outf, unsigned short* __restrict__ outb, float* __restrict__ vis)
{
  __shared__ float S[128*97];
  __shared__ float mu[128];
  __shared__ float rs[128];
  size_t base = (size_t)blockIdx.x * 12288;
  const float4* p = (const float4*)(in + base);
  for (int i = threadIdx.x; i < 3072; i += 256){
    float4 v = p[i];
    int e = i*4; int tok = e/96; int k = e - tok*96;
    float* dst = &S[tok*97 + k];
    dst[0]=v.x; dst[1]=v.y; dst[2]=v.z; dst[3]=v.w;
  }
  __syncthreads();
  if (threadIdx.x < 128){
    int tok = threadIdx.x;
    float sum=0.f, sq=0.f, vd=0.f;
    for (int k = 0; k < 96; ++k){
      float xv = S[tok*97+k];
      sum += xv; sq += xv*xv;
      if (WITH_VIS) vd += xv * Wvis[k];
    }
    float m = sum * (1.f/96.f);
    float var = sq * (1.f/96.f) - m*m;
    mu[tok] = m;
    rs[tok] = rsqrtf(fmaxf(var, 0.f) + 1e-5f);
    if (WITH_VIS) vis[(size_t)blockIdx.x*128 + tok] = sigf(vd + bvis[0]);
  }
  __syncthreads();
  for (int i = threadIdx.x; i < 12288; i += 256){
    int tok = i/96; int k = i - tok*96;
    float val = (S[tok*97+k] - mu[tok]) * rs[tok] * g[k] + bta[k];
    if (outf) outf[base + i] = val;
    outb[base + i] = f2b(val);
  }
}

// ---------------- generic token GEMM: (36864 x 96) bf16 @ BT(NO x 96) bf16 ----------------
template<int NF, class Epi>
__global__ __launch_bounds__(256) void tokgemm96(const unsigned short* __restrict__ A,
    const unsigned short* __restrict__ BT, Epi epi)
{
  int wid = threadIdx.x >> 6, lane = threadIdx.x & 63;
  int m0 = (blockIdx.x*4 + wid)*32;
  int l15 = lane & 15, q = lane >> 4;
  f4v acc[2][NF];
  #pragma unroll
  for (int i=0;i<2;++i)
    #pragma unroll
    for (int j=0;j<NF;++j)
      #pragma unroll
      for (int r=0;r<4;++r) acc[i][j][r] = 0.f;
  const bf8v* a0p = (const bf8v*)(A) + (size_t)(m0 + l15)*12 + q;
  const bf8v* a1p = a0p + 192;
  const bf8v* bp  = (const bf8v*)(BT) + (size_t)l15*12 + q;
  #pragma unroll
  for (int ks = 0; ks < 3; ++ks){
    bf8v a0 = a0p[ks*4];
    bf8v a1 = a1p[ks*4];
    #pragma unroll
    for (int nf = 0; nf < NF; ++nf){
      bf8v bb = bp[nf*192 + ks*4];
      acc[0][nf] = __builtin_amdgcn_mfma_f32_16x16x32_bf16(a0, bb, acc[0][nf], 0, 0, 0);
      acc[1][nf] = __builtin_amdgcn_mfma_f32_16x16x32_bf16(a1, bb, acc[1][nf], 0, 0, 0);
    }
  }
  #pragma unroll
  for (int mf=0; mf<2; ++mf)
    #pragma unroll
    for (int nf=0; nf<NF; ++nf)
      #pragma unroll
      for (int r=0; r<4; ++r)
        epi(m0 + mf*16 + q*4 + r, nf*16 + l15, acc[mf][nf][r]);
}

struct GateEpi {
  const float* bg; unsigned short* gate;
  __device__ void operator()(int m, int n, float v) const {
    gate[(size_t)m*96 + n] = f2b(sigf(v + bg[n]));
  }
};
struct WinEpi {
  const float* vis; unsigned short* xin; unsigned short* zsv;
  __device__ void operator()(int m, int n, float v) const {
    if (n < 96) xin[(size_t)m*96 + n] = f2b(v);
    else {
      float s = v * sigf(v);
      zsv[(size_t)m*96 + (n-96)] = f2b(s * vis[m]);
    }
  }
};
struct XfoldEpi {
  const float* bdt; unsigned short* dt; unsigned short* bc;
  __device__ void operator()(int m, int n, float v) const {
    if (n < 96){
      float x = v + bdt[n];
      float sp = (x > 20.f) ? x : __logf(1.f + __expf(x));
      dt[(size_t)m*96 + n] = f2b(sp);
    } else {
      bc[(size_t)m*32 + (n-96)] = f2b(v);
    }
  }
};
struct WoutEpi {
  const unsigned short* gate; float* tokens;
  __device__ void operator()(int m, int n, float v) const {
    size_t i = (size_t)m*96 + n;
    tokens[i] = tokens[i] + v * b2f(gate[i]);
  }
};

// ---------------- causal depthwise conv1d (k=3) + silu -> xsb (bf16) ----------------
__global__ __launch_bounds__(256) void k_conv(const unsigned short* __restrict__ xin,
    const float* __restrict__ cw, unsigned short* __restrict__ xsb)
{
  int gidx = blockIdx.x*256 + threadIdx.x;   // exact 3538944
  int m = gidx / 96; int d = gidx - m*96; int t = m % 576;
  float w0 = cw[d*3+0], w1 = cw[d*3+1], w2 = cw[d*3+2];
  float v = w2 * b2f(xin[gidx]);
  if (t >= 1) v += w1 * b2f(xin[gidx - 96]);
  if (t >= 2) v += w0 * b2f(xin[gidx - 192]);
  float s = v * sigf(v);
  xsb[gidx] = f2b(s);
}

// ---------------- selective scan: chunked 2-pass with in-LDS combine ----------------
// grid: 64 b x 6 dgroups; block: 384 = 24 chunks x 16 d
__global__ __launch_bounds__(384) void k_scan(const unsigned short* __restrict__ dt,
    const unsigned short* __restrict__ xsb, const unsigned short* __restrict__ bc,
    const unsigned short* __restrict__ zsv, const float* __restrict__ Amat,
    const float* __restrict__ Dw, unsigned short* __restrict__ y2)
{
  __shared__ float Ul[24*16*17];
  __shared__ float Sl[24*16];
  int b = blockIdx.x / 6; int dg = blockIdx.x - b*6;
  int tid = threadIdx.x;
  int c = tid >> 4; int dl = tid & 15; int d = dg*16 + dl;
  float As[16];
  #pragma unroll
  for (int s = 0; s < 16; s += 4){
    float4 t4 = *(const float4*)(Amat + d*16 + s);
    As[s]=t4.x; As[s+1]=t4.y; As[s+2]=t4.z; As[s+3]=t4.w;
  }
  float h[16];
  #pragma unroll
  for (int s=0;s<16;++s) h[s]=0.f;
  float sdt = 0.f;
  int tbase = b*576 + c*24;
  // pass 1: from zero state, accumulate U and sum(dt)
  for (int i = 0; i < 24; ++i){
    size_t m = (size_t)(tbase + i);
    float dtv = b2f(dt[m*96 + d]);
    float dtx = dtv * b2f(xsb[m*96 + d]);
    const uint4* bp = (const uint4*)(bc + m*32);
    float Bv[16];
    unpack8(bp[0], Bv); unpack8(bp[1], Bv+8);
    sdt += dtv;
    #pragma unroll
    for (int s=0;s<16;++s) h[s] = __expf(As[s]*dtv)*h[s] + dtx*Bv[s];
  }
  {
    int base = (c*16 + dl)*17;
    #pragma unroll
    for (int s=0;s<16;++s) Ul[base + s] = h[s];
    Sl[c*16 + dl] = sdt;
  }
  __syncthreads();
  // combine: serial over chunks; Ul[cc] becomes inclusive prefix state
  if (tid < 256){
    int dl2 = tid >> 4, s2 = tid & 15;
    float A2 = Amat[(dg*16 + dl2)*16 + s2];
    float hh = 0.f;
    for (int cc = 0; cc < 24; ++cc){
      float u = Ul[(cc*16 + dl2)*17 + s2];
      float ss = Sl[cc*16 + dl2];
      hh = __expf(A2*ss)*hh + u;
      Ul[(cc*16 + dl2)*17 + s2] = hh;
    }
  }
  __syncthreads();
  // pass 2: correct initial state, emit y fused with D*xs, silu(z)*vis
  if (c == 0){
    #pragma unroll
    for (int s=0;s<16;++s) h[s] = 0.f;
  } else {
    int base = ((c-1)*16 + dl)*17;
    #pragma unroll
    for (int s=0;s<16;++s) h[s] = Ul[base + s];
  }
  float Dd = Dw[d];
  for (int i = 0; i < 24; ++i){
    size_t m = (size_t)(tbase + i);
    float dtv = b2f(dt[m*96 + d]);
    float xv = b2f(xsb[m*96 + d]);
    float dtx = dtv * xv;
    const uint4* bp = (const uint4*)(bc + m*32);
    float Bv[16], Cv[16];
    unpack8(bp[0], Bv); unpack8(bp[1], Bv+8);
    unpack8(bp[2], Cv); unpack8(bp[3], Cv+8);
    float p0=0.f,p1=0.f,p2=0.f,p3=0.f;
    #pragma unroll
    for (int s=0;s<16;s+=4){
      h[s+0] = __expf(As[s+0]*dtv)*h[s+0] + dtx*Bv[s+0]; p0 += h[s+0]*Cv[s+0];
      h[s+1] = __expf(As[s+1]*dtv)*h[s+1] + dtx*Bv[s+1]; p1 += h[s+1]*Cv[s+1];
      h[s+2] = __expf(As[s+2]*dtv)*h[s+2] + dtx*Bv[s+2]; p2 += h[s+2]*Cv[s+2];
      h[s+3] = __expf(As[s+3]*dtv)*h[s+3] + dtx*Bv[s+3]; p3 += h[s+3]*Cv[s+3];
    }
    float y = (p0+p1) + (p2+p3);
    float yv = (y + Dd*xv) * b2f(zsv[m*96 + d]);
    y2[m*96 + d] = f2b(yv);
  }
}

// ---------------- head: depthwise 3x3 + BN + silu + linear heads ----------------
__global__ __launch_bounds__(256) void k_head(const float* __restrict__ tokens,
    const float* __restrict__ hdw, const float* __restrict__ bng,
    const float* __restrict__ bnb, const float* __restrict__ bnm,
    const float* __restrict__ bnv, const float* __restrict__ Wheat,
    const float* __restrict__ bheat, const float* __restrict__ Woff,
    const float* __restrict__ boff, const float* __restrict__ Wsize,
    const float* __restrict__ bsize, float* __restrict__ out)
{
  __shared__ float ft[3*2304];
  __shared__ float act[2304];
  int b = blockIdx.x / 24; int h = blockIdx.x - b*24;
  for (int i = threadIdx.x; i < 3*2304; i += 256){
    int rr = i / 2304; int j = i - rr*2304;
    int hh = h + rr - 1;
    float v = 0.f;
    if (hh >= 0 && hh < 24) v = tokens[((size_t)b*576 + hh*24)*96 + j];
    ft[rr*2304 + j] = v;
  }
  __syncthreads();
  for (int i = threadIdx.x; i < 2304; i += 256){
    int w = i / 96; int cc = i - w*96;
    float g = 0.f;
    #pragma unroll
    for (int dh = 0; dh < 3; ++dh){
      #pragma unroll
      for (int dw = 0; dw < 3; ++dw){
        int ww = w + dw - 1;
        if (ww >= 0 && ww < 24) g += ft[dh*2304 + ww*96 + cc] * hdw[cc*9 + dh*3 + dw];
      }
    }
    float gn = (g - bnm[cc]) * rsqrtf(bnv[cc] + 1e-5f);
    float a = gn * bng[cc] + bnb[cc];
    act[i] = a * sigf(a);
  }
  __syncthreads();
  int tid = threadIdx.x;
  if (tid < 120){
    int o = tid / 24; int w = tid - o*24;
    float s = 0.f;
    for (int cc = 0; cc < 96; ++cc) s += act[w*96 + cc] * Wheat[o*96 + cc];
    s += bheat[o];
    out[(size_t)b*2880 + o*576 + h*24 + w] = s;
  } else if (tid >= 128 && tid < 224){
    int idx = tid - 128; int o2 = idx / 24; int w = idx - o2*24;
    const float* W = (o2 < 2) ? Woff : Wsize;
    int o = o2 & 1;
    float s = 0.f;
    for (int cc = 0; cc < 96; ++cc) s += ft[2304 + w*96 + cc] * W[o*96 + cc];
    s += ((o2 < 2) ? boff : bsize)[o];
    size_t baseo = (o2 < 2) ? (size_t)184320 : (size_t)258048;
    out[baseo + (size_t)b*1152 + o*576 + h*24 + w] = s;
  }
}

// ---------------- host ----------------
extern "C" void kernel_launch(void* const* d_in, const int* in_sizes, int n_in,
                              void* d_out, int out_size, void* d_ws, size_t ws_size,
                              hipStream_t stream)
{
  (void)in_sizes; (void)n_in; (void)out_size; (void)ws_size;
  const float* x      = (const float*)d_in[0];
  const float* Wpe    = (const float*)d_in[1];
  const float* bpe    = (const float*)d_in[2];
  const float* Wvis   = (const float*)d_in[3];
  const float* bvis   = (const float*)d_in[4];
  const float* dng    = (const float*)d_in[5];
  const float* dnb    = (const float*)d_in[6];
  const float* Wgate  = (const float*)d_in[7];
  const float* bgate  = (const float*)d_in[8];
  const float* lng    = (const float*)d_in[9];
  const float* lnb    = (const float*)d_in[10];
  const float* Win    = (const float*)d_in[11];
  const float* convw  = (const float*)d_in[12];
  const float* Wxproj = (const float*)d_in[13];
  const float* Wdt    = (const float*)d_in[14];
  const float* bdt    = (const float*)d_in[15];
  const float* Alog   = (const float*)d_in[16];
  const float* Dw     = (const float*)d_in[17];
  const float* Wout   = (const float*)d_in[18];
  const float* hddw   = (const float*)d_in[19];
  const float* bng    = (const float*)d_in[20];
  const float* bnb    = (const float*)d_in[21];
  const float* bnm    = (const float*)d_in[22];
  const float* bnv    = (const float*)d_in[23];
  const float* Wheat  = (const float*)d_in[24];
  const float* bheat  = (const float*)d_in[25];
  const float* Woff   = (const float*)d_in[26];
  const float* boff   = (const float*)d_in[27];
  const float* Wsize  = (const float*)d_in[28];
  const float* bsize  = (const float*)d_in[29];
  float* out = (float*)d_out;

  char* ws = (char*)d_ws;
  unsigned short* xlog  = (unsigned short*)(ws + WS_XLOG);
  float*          tokraw= (float*)(ws + WS_TOKRAW);
  float*          vis   = (float*)(ws + WS_VIS);
  unsigned short* WgT   = (unsigned short*)(ws + WS_WGT);
  unsigned short* WiT   = (unsigned short*)(ws + WS_WIT);
  unsigned short* WxT   = (unsigned short*)(ws + WS_WXT);
  unsigned short* WoT   = (unsigned short*)(ws + WS_WOT);
  float*          Amat  = (float*)(ws + WS_AMAT);
  unsigned short* WpeB  = (unsigned short*)(ws + WS_WPE);
  float*          tok   = (float*)(ws + WS_TOK);
  unsigned short* gate  = (unsigned short*)(ws + WS_GATE);
  unsigned short* dnbf  = (unsigned short*)(ws + WS_DNB);
  unsigned short* xsb   = (unsigned short*)(ws + WS_XSB);
  unsigned short* hb    = (unsigned short*)(ws + WS_HB);
  unsigned short* y2    = (unsigned short*)(ws + WS_Y2);
  unsigned short* xinb  = (unsigned short*)(ws + WS_XIN);
  unsigned short* zsvb  = (unsigned short*)(ws + WS_ZSV);
  unsigned short* dtb   = (unsigned short*)(ws + WS_DT);
  unsigned short* bcb   = (unsigned short*)(ws + WS_BC);

  k_prep<<<1, 256, 0, stream>>>(Wgate, Win, Wxproj, Wdt, Wout, Alog, Wpe,
                                WgT, WiT, WxT, WoT, Amat, WpeB);
  k_blur<<<4608, 256, 0, stream>>>(x, xlog);
  k_patch<<<288, 256, 0, stream>>>(xlog, WpeB, bpe, tokraw);
  k_ln<true><<<288, 256, 0, stream>>>(tokraw, dng, dnb, Wvis, bvis, tok, dnbf, vis);
  tokgemm96<6, GateEpi><<<288, 256, 0, stream>>>(dnbf, WgT, GateEpi{bgate, gate});

  for (int rep = 0; rep < 4; ++rep){
    k_ln<false><<<288, 256, 0, stream>>>(tok, lng, lnb, nullptr, nullptr, nullptr, hb, nullptr);
    tokgemm96<12, WinEpi><<<288, 256, 0, stream>>>(hb, WiT, WinEpi{vis, xinb, zsvb});
    k_conv<<<13824, 256, 0, stream>>>(xinb, convw, xsb);
    tokgemm96<8, XfoldEpi><<<288, 256, 0, stream>>>(xsb, WxT, XfoldEpi{bdt, dtb, bcb});
    k_scan<<<384, 384, 0, stream>>>(dtb, xsb, bcb, zsvb, Amat, Dw, y2);
    tokgemm96<6, WoutEpi><<<288, 256, 0, stream>>>(y2, WoT, WoutEpi{gate, tok});
  }

  k_head<<<1536, 256, 0, stream>>>(tok, hddw, bng, bnb, bnm, bnv,
                                   Wheat, bheat, Woff, boff, Wsize, bsize, out);
}

// Round 5
// 898.982 us; speedup vs baseline: 1.2138x; 1.1108x over previous
//
#include <hip/hip_runtime.h>

#define DEVINL __device__ __forceinline__

typedef __attribute__((ext_vector_type(8))) short bf8v;
typedef __attribute__((ext_vector_type(4))) float f4v;

DEVINL float b2f(unsigned short u){ union{unsigned int i; float f;} x; x.i = ((unsigned int)u)<<16; return x.f; }
DEVINL unsigned short f2b(float f){ union{float f; unsigned int i;} x; x.f = f; unsigned int r = x.i + 0x7FFFu + ((x.i>>16)&1u); return (unsigned short)(r>>16); }
DEVINL float sigf(float v){ return 1.f/(1.f + __expf(-v)); }
DEVINL void unpack8(const uint4 u, float* d){
  d[0]=b2f((unsigned short)(u.x)); d[1]=b2f((unsigned short)(u.x>>16));
  d[2]=b2f((unsigned short)(u.y)); d[3]=b2f((unsigned short)(u.y>>16));
  d[4]=b2f((unsigned short)(u.z)); d[5]=b2f((unsigned short)(u.z>>16));
  d[6]=b2f((unsigned short)(u.w)); d[7]=b2f((unsigned short)(u.w>>16));
}

// B=64 IMG=384 PS=16 DM=96 DS=16 DI=96 DT_RANK=6 NREP=4 NCLS=5 HP=24 N=576, M=36864
// External I/O: FLOAT32. Internal GEMM operands: bf16 in workspace.

// ---------------- workspace layout (bytes; high-water ~71.2 MB) ----------------
#define WS_XLOG   ((size_t)0)            // bf16 28311552 el (k_blur -> k_patch)
#define WS_TOKRAW ((size_t)56623104)     // f32 3538944 el (k_patch -> k_ln<true>)
#define WS_VIS    ((size_t)70778880)     // f32 36864     [permanent]
#define WS_WGT    ((size_t)70926336)     // bf16 96*96
#define WS_WIT    ((size_t)70944768)     // bf16 192*96
#define WS_WXT    ((size_t)70981632)     // bf16 128*96
#define WS_WOT    ((size_t)71006208)     // bf16 96*96
#define WS_AMAT   ((size_t)71024640)     // f32 96*16
#define WS_WPE    ((size_t)71030784)     // bf16 96*768  -> end 71178240
// Phase B (inside dead xlog/tokraw region):
#define WS_TOK    ((size_t)0)            // f32 3538944 (residual stream)
#define WS_GATE   ((size_t)14155776)     // bf16 3538944
#define WS_DNB    ((size_t)21233664)     // bf16 (alias XSB; dnb dead before first conv)
#define WS_XSB    ((size_t)21233664)     // bf16 3538944
#define WS_HB     ((size_t)28311552)     // bf16 (alias Y2; hb dead before scan writes y2)
#define WS_Y2     ((size_t)28311552)     // bf16 3538944
#define WS_XIN    ((size_t)35389440)     // bf16 3538944
#define WS_ZSV    ((size_t)42467328)     // bf16 3538944
#define WS_DT     ((size_t)49545216)     // bf16 3538944 -> end 56623104
#define WS_BC     ((size_t)56623104)     // bf16 36864*32 -> end 58982400 (dead tokraw)

// ---------------- prep: bf16-ify weights (transposed), W_dt fold, A matrix ----------------
// Grid-parallel: 128 blocks x 256 threads (R4: single block was 103 us, latency-bound,
// VALUBusy 0.03% — 255 CUs idle). Stride = 32768.
#define PREP_STRIDE (128*256)
__global__ __launch_bounds__(256) void k_prep(
    const float* __restrict__ Wgate, const float* __restrict__ Win,
    const float* __restrict__ Wxproj, const float* __restrict__ Wdt,
    const float* __restrict__ Wout, const float* __restrict__ Alog,
    const float* __restrict__ Wpe,
    unsigned short* __restrict__ WgT, unsigned short* __restrict__ WiT,
    unsigned short* __restrict__ WxT, unsigned short* __restrict__ WoT,
    float* __restrict__ Amat, unsigned short* __restrict__ WpeB)
{
  int gtid = blockIdx.x*256 + threadIdx.x;
  for (int i = gtid; i < 9216; i += PREP_STRIDE){
    int n = i/96, k = i - n*96;
    WgT[n*96+k] = f2b(Wgate[k*96+n]);
    WoT[n*96+k] = f2b(Wout[k*96+n]);
  }
  for (int i = gtid; i < 18432; i += PREP_STRIDE){
    int n = i/96, k = i - n*96;
    WiT[n*96+k] = f2b(Win[k*192+n]);
  }
  for (int i = gtid; i < 12288; i += PREP_STRIDE){
    int n = i/96, k = i - n*96;
    if (n < 96){
      float s = 0.f;
      for (int r = 0; r < 6; ++r) s += Wxproj[k*38+r] * Wdt[r*96+n];
      WxT[n*96+k] = f2b(s);
    } else {
      WxT[n*96+k] = f2b(Wxproj[k*38 + 6 + (n-96)]);
    }
  }
  for (int i = gtid; i < 1536; i += PREP_STRIDE) Amat[i] = -__expf(Alog[i]);
  for (int i = gtid; i < 73728; i += PREP_STRIDE) WpeB[i] = f2b(Wpe[i]);  // (n, c, ph, pw) row-major
}

// ---------------- K1: 5x5 box blur + log1p diff -> xlog (bf16) ----------------
__global__ __launch_bounds__(256) void k_blur(const float* __restrict__ x,
                                              unsigned short* __restrict__ xlog)
{
  __shared__ float xt[20*384];     // raw rows y0-2 .. y0+17
  __shared__ float vt[16*392];     // vertical 5-sums, padded 4 zeros each side
  int bid = blockIdx.x;            // 64*3*24
  int tile = bid % 24; int bc = bid / 24; int c = bc % 3; int b = bc / 3;
  const float* xin = x + (size_t)(b*3 + c) * 147456;
  unsigned short* xout = xlog + (size_t)(b*3 + c) * 147456;
  int y0 = tile * 16;
  int tid = threadIdx.x;

  // phase 1: stage 20 rows (zero-filled outside image) as float4
  #pragma unroll
  for (int k = 0; k < 8; ++k){
    int idx = tid + k*256;
    if (idx < 1920){
      int r = idx / 96; int c4 = idx - r*96;
      int gy = y0 - 2 + r;
      float4 v = make_float4(0.f,0.f,0.f,0.f);
      if (gy >= 0 && gy < 384) v = *(const float4*)(xin + gy*384 + c4*4);
      *(float4*)(xt + r*384 + c4*4) = v;
    }
  }
  // zero vt side pads: 16 rows * 8 floats
  if (tid < 128){
    int r = tid >> 3; int j = tid & 7;
    vt[r*392 + ((j < 4) ? j : (384 + j))] = 0.f;
  }
  __syncthreads();

  // phase 2: vertical 5-sums. 1536 units = (r=0..15, c4=0..95), 6 per thread.
  #pragma unroll
  for (int k = 0; k < 6; ++k){
    int unit = tid + k*256;
    int r = unit / 96; int c4 = unit - r*96;
    const float* base = xt + r*384 + c4*4;
    float4 s0 = *(const float4*)(base);
    float4 s1 = *(const float4*)(base + 384);
    float4 s2 = *(const float4*)(base + 768);
    float4 s3 = *(const float4*)(base + 1152);
    float4 s4 = *(const float4*)(base + 1536);
    float4 s;
    s.x = s0.x+s1.x+s2.x+s3.x+s4.x;
    s.y = s0.y+s1.y+s2.y+s3.y+s4.y;
    s.z = s0.z+s1.z+s2.z+s3.z+s4.z;
    s.w = s0.w+s1.w+s2.w+s3.w+s4.w;
    *(float4*)(vt + r*392 + 4 + c4*4) = s;
  }
  __syncthreads();

  // phase 3: horizontal 5-sums + log-diff + bf16 store. Same 1536-unit mapping.
  #pragma unroll
  for (int k = 0; k < 6; ++k){
    int unit = tid + k*256;
    int r = unit / 96; int c4 = unit - r*96;
    int base = r*392 + 4 + c4*4;
    float f[12];
    *(float4*)(f)   = *(const float4*)(vt + base - 4);
    *(float4*)(f+4) = *(const float4*)(vt + base);
    *(float4*)(f+8) = *(const float4*)(vt + base + 4);
    float4 xraw = *(const float4*)(xt + (r+2)*384 + c4*4);
    const float* xr = &xraw.x;
    ushort4 o;
    unsigned short* op = &o.x;
    #pragma unroll
    for (int j = 0; j < 4; ++j){
      float s = f[2+j] + f[3+j] + f[4+j] + f[5+j] + f[6+j];
      float L = fmaxf(s * 0.04f, 0.f);
      float xv = fmaxf(xr[j], 0.f);
      op[j] = f2b(__logf(1.f + xv) - __logf(1.f + L));
    }
    *(ushort4*)(xout + (y0+r)*384 + c4*4) = o;
  }
}

// ---------------- K2: patch embed (MFMA, im2col-free) -> tokens_raw f32 ----------------
__global__ __launch_bounds__(256) void k_patch(const unsigned short* __restrict__ xlog,
    const unsigned short* __restrict__ WpeB, const float* __restrict__ bpe,
    float* __restrict__ tokraw)
{
  int wid = threadIdx.x >> 6, lane = threadIdx.x & 63;
  int m0 = (blockIdx.x*4 + wid)*32;
  int l15 = lane & 15, q = lane >> 4;
  int ma0 = m0 + l15, ma1 = ma0 + 16;
  int b0 = ma0/576; int r0 = ma0 - b0*576; int hp0 = r0/24; int wp0 = r0 - hp0*24;
  int b1 = ma1/576; int r1 = ma1 - b1*576; int hp1 = r1/24; int wp1 = r1 - hp1*24;
  size_t base0 = (size_t)b0*442368 + (size_t)hp0*6144 + (size_t)wp0*16;
  size_t base1 = (size_t)b1*442368 + (size_t)hp1*6144 + (size_t)wp1*16;
  f4v acc[2][6];
  #pragma unroll
  for (int i=0;i<2;++i)
    #pragma unroll
    for (int j=0;j<6;++j)
      #pragma unroll
      for (int r=0;r<4;++r) acc[i][j][r] = 0.f;
  for (int ks = 0; ks < 24; ++ks){
    int k0 = ks*32 + q*8;
    int c  = k0 >> 8;
    int ph = (k0 >> 4) & 15;
    int pw = k0 & 15;
    size_t off = (size_t)c*147456 + (size_t)ph*384 + pw;
    bf8v a0 = *(const bf8v*)(xlog + base0 + off);
    bf8v a1 = *(const bf8v*)(xlog + base1 + off);
    #pragma unroll
    for (int nf = 0; nf < 6; ++nf){
      bf8v bb = *(const bf8v*)(WpeB + (size_t)(nf*16 + l15)*768 + k0);
      acc[0][nf] = __builtin_amdgcn_mfma_f32_16x16x32_bf16(a0, bb, acc[0][nf], 0, 0, 0);
      acc[1][nf] = __builtin_amdgcn_mfma_f32_16x16x32_bf16(a1, bb, acc[1][nf], 0, 0, 0);
    }
  }
  #pragma unroll
  for (int mf=0; mf<2; ++mf)
    #pragma unroll
    for (int nf=0; nf<6; ++nf)
      #pragma unroll
      for (int r=0; r<4; ++r){
        int m = m0 + mf*16 + q*4 + r;
        int n = nf*16 + l15;
        tokraw[(size_t)m*96 + n] = acc[mf][nf][r] + bpe[n];
      }
}

// ---------------- LayerNorm (+optional vis) ----------------
template<bool WITH_VIS>
__global__ __launch_bounds__(256) void k_ln(const float* __restrict__ in,
    const float* __restrict__ g, const float* __restrict__ bta,
    const float* __restrict__ Wvis, const float* __restrict__ bvis,
    float* __restrict__ outf, unsigned short* __restrict__ outb, float* __restrict__ vis)
{
  __shared__ float S[128*97];
  __shared__ float mu[128];
  __shared__ float rs[128];
  size_t base = (size_t)blockIdx.x * 12288;
  const float4* p = (const float4*)(in + base);
  for (int i = threadIdx.x; i < 3072; i += 256){
    float4 v = p[i];
    int e = i*4; int tok = e/96; int k = e - tok*96;
    float* dst = &S[tok*97 + k];
    dst[0]=v.x; dst[1]=v.y; dst[2]=v.z; dst[3]=v.w;
  }
  __syncthreads();
  if (threadIdx.x < 128){
    int tok = threadIdx.x;
    float sum=0.f, sq=0.f, vd=0.f;
    for (int k = 0; k < 96; ++k){
      float xv = S[tok*97+k];
      sum += xv; sq += xv*xv;
      if (WITH_VIS) vd += xv * Wvis[k];
    }
    float m = sum * (1.f/96.f);
    float var = sq * (1.f/96.f) - m*m;
    mu[tok] = m;
    rs[tok] = rsqrtf(fmaxf(var, 0.f) + 1e-5f);
    if (WITH_VIS) vis[(size_t)blockIdx.x*128 + tok] = sigf(vd + bvis[0]);
  }
  __syncthreads();
  for (int i = threadIdx.x; i < 12288; i += 256){
    int tok = i/96; int k = i - tok*96;
    float val = (S[tok*97+k] - mu[tok]) * rs[tok] * g[k] + bta[k];
    if (outf) outf[base + i] = val;
    outb[base + i] = f2b(val);
  }
}

// ---------------- generic token GEMM: (36864 x 96) bf16 @ BT(NO x 96) bf16 ----------------
template<int NF, class Epi>
__global__ __launch_bounds__(256) void tokgemm96(const unsigned short* __restrict__ A,
    const unsigned short* __restrict__ BT, Epi epi)
{
  int wid = threadIdx.x >> 6, lane = threadIdx.x & 63;
  int m0 = (blockIdx.x*4 + wid)*32;
  int l15 = lane & 15, q = lane >> 4;
  f4v acc[2][NF];
  #pragma unroll
  for (int i=0;i<2;++i)
    #pragma unroll
    for (int j=0;j<NF;++j)
      #pragma unroll
      for (int r=0;r<4;++r) acc[i][j][r] = 0.f;
  const bf8v* a0p = (const bf8v*)(A) + (size_t)(m0 + l15)*12 + q;
  const bf8v* a1p = a0p + 192;
  const bf8v* bp  = (const bf8v*)(BT) + (size_t)l15*12 + q;
  #pragma unroll
  for (int ks = 0; ks < 3; ++ks){
    bf8v a0 = a0p[ks*4];
    bf8v a1 = a1p[ks*4];
    #pragma unroll
    for (int nf = 0; nf < NF; ++nf){
      bf8v bb = bp[nf*192 + ks*4];
      acc[0][nf] = __builtin_amdgcn_mfma_f32_16x16x32_bf16(a0, bb, acc[0][nf], 0, 0, 0);
      acc[1][nf] = __builtin_amdgcn_mfma_f32_16x16x32_bf16(a1, bb, acc[1][nf], 0, 0, 0);
    }
  }
  #pragma unroll
  for (int mf=0; mf<2; ++mf)
    #pragma unroll
    for (int nf=0; nf<NF; ++nf)
      #pragma unroll
      for (int r=0; r<4; ++r)
        epi(m0 + mf*16 + q*4 + r, nf*16 + l15, acc[mf][nf][r]);
}

struct GateEpi {
  const float* bg; unsigned short* gate;
  __device__ void operator()(int m, int n, float v) const {
    gate[(size_t)m*96 + n] = f2b(sigf(v + bg[n]));
  }
};
struct WinEpi {
  const float* vis; unsigned short* xin; unsigned short* zsv;
  __device__ void operator()(int m, int n, float v) const {
    if (n < 96) xin[(size_t)m*96 + n] = f2b(v);
    else {
      float s = v * sigf(v);
      zsv[(size_t)m*96 + (n-96)] = f2b(s * vis[m]);
    }
  }
};
struct XfoldEpi {
  const float* bdt; unsigned short* dt; unsigned short* bc;
  __device__ void operator()(int m, int n, float v) const {
    if (n < 96){
      float x = v + bdt[n];
      float sp = (x > 20.f) ? x : __logf(1.f + __expf(x));
      dt[(size_t)m*96 + n] = f2b(sp);
    } else {
      bc[(size_t)m*32 + (n-96)] = f2b(v);
    }
  }
};
struct WoutEpi {
  const unsigned short* gate; float* tokens;
  __device__ void operator()(int m, int n, float v) const {
    size_t i = (size_t)m*96 + n;
    tokens[i] = tokens[i] + v * b2f(gate[i]);
  }
};

// ---------------- causal depthwise conv1d (k=3) + silu -> xsb (bf16) ----------------
__global__ __launch_bounds__(256) void k_conv(const unsigned short* __restrict__ xin,
    const float* __restrict__ cw, unsigned short* __restrict__ xsb)
{
  int gidx = blockIdx.x*256 + threadIdx.x;   // exact 3538944
  int m = gidx / 96; int d = gidx - m*96; int t = m % 576;
  float w0 = cw[d*3+0], w1 = cw[d*3+1], w2 = cw[d*3+2];
  float v = w2 * b2f(xin[gidx]);
  if (t >= 1) v += w1 * b2f(xin[gidx - 96]);
  if (t >= 2) v += w0 * b2f(xin[gidx - 192]);
  float s = v * sigf(v);
  xsb[gidx] = f2b(s);
}

// ---------------- selective scan: chunked 2-pass with in-LDS combine ----------------
// grid: 64 b x 6 dgroups; block: 384 = 24 chunks x 16 d
__global__ __launch_bounds__(384) void k_scan(const unsigned short* __restrict__ dt,
    const unsigned short* __restrict__ xsb, const unsigned short* __restrict__ bc,
    const unsigned short* __restrict__ zsv, const float* __restrict__ Amat,
    const float* __restrict__ Dw, unsigned short* __restrict__ y2)
{
  __shared__ float Ul[24*16*17];
  __shared__ float Sl[24*16];
  int b = blockIdx.x / 6; int dg = blockIdx.x - b*6;
  int tid = threadIdx.x;
  int c = tid >> 4; int dl = tid & 15; int d = dg*16 + dl;
  float As[16];
  #pragma unroll
  for (int s = 0; s < 16; s += 4){
    float4 t4 = *(const float4*)(Amat + d*16 + s);
    As[s]=t4.x; As[s+1]=t4.y; As[s+2]=t4.z; As[s+3]=t4.w;
  }
  float h[16];
  #pragma unroll
  for (int s=0;s<16;++s) h[s]=0.f;
  float sdt = 0.f;
  int tbase = b*576 + c*24;
  // pass 1: from zero state, accumulate U and sum(dt)
  for (int i = 0; i < 24; ++i){
    size_t m = (size_t)(tbase + i);
    float dtv = b2f(dt[m*96 + d]);
    float dtx = dtv * b2f(xsb[m*96 + d]);
    const uint4* bp = (const uint4*)(bc + m*32);
    float Bv[16];
    unpack8(bp[0], Bv); unpack8(bp[1], Bv+8);
    sdt += dtv;
    #pragma unroll
    for (int s=0;s<16;++s) h[s] = __expf(As[s]*dtv)*h[s] + dtx*Bv[s];
  }
  {
    int base = (c*16 + dl)*17;
    #pragma unroll
    for (int s=0;s<16;++s) Ul[base + s] = h[s];
    Sl[c*16 + dl] = sdt;
  }
  __syncthreads();
  // combine: serial over chunks; Ul[cc] becomes inclusive prefix state
  if (tid < 256){
    int dl2 = tid >> 4, s2 = tid & 15;
    float A2 = Amat[(dg*16 + dl2)*16 + s2];
    float hh = 0.f;
    for (int cc = 0; cc < 24; ++cc){
      float u = Ul[(cc*16 + dl2)*17 + s2];
      float ss = Sl[cc*16 + dl2];
      hh = __expf(A2*ss)*hh + u;
      Ul[(cc*16 + dl2)*17 + s2] = hh;
    }
  }
  __syncthreads();
  // pass 2: correct initial state, emit y fused with D*xs, silu(z)*vis
  if (c == 0){
    #pragma unroll
    for (int s=0;s<16;++s) h[s] = 0.f;
  } else {
    int base = ((c-1)*16 + dl)*17;
    #pragma unroll
    for (int s=0;s<16;++s) h[s] = Ul[base + s];
  }
  float Dd = Dw[d];
  for (int i = 0; i < 24; ++i){
    size_t m = (size_t)(tbase + i);
    float dtv = b2f(dt[m*96 + d]);
    float xv = b2f(xsb[m*96 + d]);
    float dtx = dtv * xv;
    const uint4* bp = (const uint4*)(bc + m*32);
    float Bv[16], Cv[16];
    unpack8(bp[0], Bv); unpack8(bp[1], Bv+8);
    unpack8(bp[2], Cv); unpack8(bp[3], Cv+8);
    float p0=0.f,p1=0.f,p2=0.f,p3=0.f;
    #pragma unroll
    for (int s=0;s<16;s+=4){
      h[s+0] = __expf(As[s+0]*dtv)*h[s+0] + dtx*Bv[s+0]; p0 += h[s+0]*Cv[s+0];
      h[s+1] = __expf(As[s+1]*dtv)*h[s+1] + dtx*Bv[s+1]; p1 += h[s+1]*Cv[s+1];
      h[s+2] = __expf(As[s+2]*dtv)*h[s+2] + dtx*Bv[s+2]; p2 += h[s+2]*Cv[s+2];
      h[s+3] = __expf(As[s+3]*dtv)*h[s+3] + dtx*Bv[s+3]; p3 += h[s+3]*Cv[s+3];
    }
    float y = (p0+p1) + (p2+p3);
    float yv = (y + Dd*xv) * b2f(zsv[m*96 + d]);
    y2[m*96 + d] = f2b(yv);
  }
}

// ---------------- head: depthwise 3x3 + BN + silu + linear heads ----------------
__global__ __launch_bounds__(256) void k_head(const float* __restrict__ tokens,
    const float* __restrict__ hdw, const float* __restrict__ bng,
    const float* __restrict__ bnb, const float* __restrict__ bnm,
    const float* __restrict__ bnv, const float* __restrict__ Wheat,
    const float* __restrict__ bheat, const float* __restrict__ Woff,
    const float* __restrict__ boff, const float* __restrict__ Wsize,
    const float* __restrict__ bsize, float* __restrict__ out)
{
  __shared__ float ft[3*2304];
  __shared__ float act[2304];
  int b = blockIdx.x / 24; int h = blockIdx.x - b*24;
  for (int i = threadIdx.x; i < 3*2304; i += 256){
    int rr = i / 2304; int j = i - rr*2304;
    int hh = h + rr - 1;
    float v = 0.f;
    if (hh >= 0 && hh < 24) v = tokens[((size_t)b*576 + hh*24)*96 + j];
    ft[rr*2304 + j] = v;
  }
  __syncthreads();
  for (int i = threadIdx.x; i < 2304; i += 256){
    int w = i / 96; int cc = i - w*96;
    float g = 0.f;
    #pragma unroll
    for (int dh = 0; dh < 3; ++dh){
      #pragma unroll
      for (int dw = 0; dw < 3; ++dw){
        int ww = w + dw - 1;
        if (ww >= 0 && ww < 24) g += ft[dh*2304 + ww*96 + cc] * hdw[cc*9 + dh*3 + dw];
      }
    }
    float gn = (g - bnm[cc]) * rsqrtf(bnv[cc] + 1e-5f);
    float a = gn * bng[cc] + bnb[cc];
    act[i] = a * sigf(a);
  }
  __syncthreads();
  int tid = threadIdx.x;
  if (tid < 120){
    int o = tid / 24; int w = tid - o*24;
    float s = 0.f;
    for (int cc = 0; cc < 96; ++cc) s += act[w*96 + cc] * Wheat[o*96 + cc];
    s += bheat[o];
    out[(size_t)b*2880 + o*576 + h*24 + w] = s;
  } else if (tid >= 128 && tid < 224){
    int idx = tid - 128; int o2 = idx / 24; int w = idx - o2*24;
    const float* W = (o2 < 2) ? Woff : Wsize;
    int o = o2 & 1;
    float s = 0.f;
    for (int cc = 0; cc < 96; ++cc) s += ft[2304 + w*96 + cc] * W[o*96 + cc];
    s += ((o2 < 2) ? boff : bsize)[o];
    size_t baseo = (o2 < 2) ? (size_t)184320 : (size_t)258048;
    out[baseo + (size_t)b*1152 + o*576 + h*24 + w] = s;
  }
}

// ---------------- host ----------------
extern "C" void kernel_launch(void* const* d_in, const int* in_sizes, int n_in,
                              void* d_out, int out_size, void* d_ws, size_t ws_size,
                              hipStream_t stream)
{
  (void)in_sizes; (void)n_in; (void)out_size; (void)ws_size;
  const float* x      = (const float*)d_in[0];
  const float* Wpe    = (const float*)d_in[1];
  const float* bpe    = (const float*)d_in[2];
  const float* Wvis   = (const float*)d_in[3];
  const float* bvis   = (const float*)d_in[4];
  const float* dng    = (const float*)d_in[5];
  const float* dnb    = (const float*)d_in[6];
  const float* Wgate  = (const float*)d_in[7];
  const float* bgate  = (const float*)d_in[8];
  const float* lng    = (const float*)d_in[9];
  const float* lnb    = (const float*)d_in[10];
  const float* Win    = (const float*)d_in[11];
  const float* convw  = (const float*)d_in[12];
  const float* Wxproj = (const float*)d_in[13];
  const float* Wdt    = (const float*)d_in[14];
  const float* bdt    = (const float*)d_in[15];
  const float* Alog   = (const float*)d_in[16];
  const float* Dw     = (const float*)d_in[17];
  const float* Wout   = (const float*)d_in[18];
  const float* hddw   = (const float*)d_in[19];
  const float* bng    = (const float*)d_in[20];
  const float* bnb    = (const float*)d_in[21];
  const float* bnm    = (const float*)d_in[22];
  const float* bnv    = (const float*)d_in[23];
  const float* Wheat  = (const float*)d_in[24];
  const float* bheat  = (const float*)d_in[25];
  const float* Woff   = (const float*)d_in[26];
  const float* boff   = (const float*)d_in[27];
  const float* Wsize  = (const float*)d_in[28];
  const float* bsize  = (const float*)d_in[29];
  float* out = (float*)d_out;

  char* ws = (char*)d_ws;
  unsigned short* xlog  = (unsigned short*)(ws + WS_XLOG);
  float*          tokraw= (float*)(ws + WS_TOKRAW);
  float*          vis   = (float*)(ws + WS_VIS);
  unsigned short* WgT   = (unsigned short*)(ws + WS_WGT);
  unsigned short* WiT   = (unsigned short*)(ws + WS_WIT);
  unsigned short* WxT   = (unsigned short*)(ws + WS_WXT);
  unsigned short* WoT   = (unsigned short*)(ws + WS_WOT);
  float*          Amat  = (float*)(ws + WS_AMAT);
  unsigned short* WpeB  = (unsigned short*)(ws + WS_WPE);
  float*          tok   = (float*)(ws + WS_TOK);
  unsigned short* gate  = (unsigned short*)(ws + WS_GATE);
  unsigned short* dnbf  = (unsigned short*)(ws + WS_DNB);
  unsigned short* xsb   = (unsigned short*)(ws + WS_XSB);
  unsigned short* hb    = (unsigned short*)(ws + WS_HB);
  unsigned short* y2    = (unsigned short*)(ws + WS_Y2);
  unsigned short* xinb  = (unsigned short*)(ws + WS_XIN);
  unsigned short* zsvb  = (unsigned short*)(ws + WS_ZSV);
  unsigned short* dtb   = (unsigned short*)(ws + WS_DT);
  unsigned short* bcb   = (unsigned short*)(ws + WS_BC);

  k_prep<<<128, 256, 0, stream>>>(Wgate, Win, Wxproj, Wdt, Wout, Alog, Wpe,
                                  WgT, WiT, WxT, WoT, Amat, WpeB);
  k_blur<<<4608, 256, 0, stream>>>(x, xlog);
  k_patch<<<288, 256, 0, stream>>>(xlog, WpeB, bpe, tokraw);
  k_ln<true><<<288, 256, 0, stream>>>(tokraw, dng, dnb, Wvis, bvis, tok, dnbf, vis);
  tokgemm96<6, GateEpi><<<288, 256, 0, stream>>>(dnbf, WgT, GateEpi{bgate, gate});

  for (int rep = 0; rep < 4; ++rep){
    k_ln<false><<<288, 256, 0, stream>>>(tok, lng, lnb, nullptr, nullptr, nullptr, hb, nullptr);
    tokgemm96<12, WinEpi><<<288, 256, 0, stream>>>(hb, WiT, WinEpi{vis, xinb, zsvb});
    k_conv<<<13824, 256, 0, stream>>>(xinb, convw, xsb);
    tokgemm96<8, XfoldEpi><<<288, 256, 0, stream>>>(xsb, WxT, XfoldEpi{bdt, dtb, bcb});
    k_scan<<<384, 384, 0, stream>>>(dtb, xsb, bcb, zsvb, Amat, Dw, y2);
    tokgemm96<6, WoutEpi><<<288, 256, 0, stream>>>(y2, WoT, WoutEpi{gate, tok});
  }

  k_head<<<1536, 256, 0, stream>>>(tok, hddw, bng, bnb, bnm, bnv,
                                   Wheat, bheat, Woff, boff, Wsize, bsize, out);
}

// Round 6
// 832.347 us; speedup vs baseline: 1.3110x; 1.0801x over previous
//
#include <hip/hip_runtime.h>

#define DEVINL __device__ __forceinline__

typedef __attribute__((ext_vector_type(8))) short bf8v;
typedef __attribute__((ext_vector_type(4))) float f4v;

DEVINL float b2f(unsigned short u){ union{unsigned int i; float f;} x; x.i = ((unsigned int)u)<<16; return x.f; }
DEVINL unsigned short f2b(float f){ union{float f; unsigned int i;} x; x.f = f; unsigned int r = x.i + 0x7FFFu + ((x.i>>16)&1u); return (unsigned short)(r>>16); }
DEVINL float sigf(float v){ return 1.f/(1.f + __expf(-v)); }
DEVINL void unpack8(const uint4 u, float* d){
  d[0]=b2f((unsigned short)(u.x)); d[1]=b2f((unsigned short)(u.x>>16));
  d[2]=b2f((unsigned short)(u.y)); d[3]=b2f((unsigned short)(u.y>>16));
  d[4]=b2f((unsigned short)(u.z)); d[5]=b2f((unsigned short)(u.z>>16));
  d[6]=b2f((unsigned short)(u.w)); d[7]=b2f((unsigned short)(u.w>>16));
}
DEVINL uint4 pack8(const float* s){
  uint4 u;
  u.x = (unsigned int)f2b(s[0]) | ((unsigned int)f2b(s[1])<<16);
  u.y = (unsigned int)f2b(s[2]) | ((unsigned int)f2b(s[3])<<16);
  u.z = (unsigned int)f2b(s[4]) | ((unsigned int)f2b(s[5])<<16);
  u.w = (unsigned int)f2b(s[6]) | ((unsigned int)f2b(s[7])<<16);
  return u;
}
union FragU { uint4 u; bf8v v; };

// B=64 IMG=384 PS=16 DM=96 DS=16 DI=96 DT_RANK=6 NREP=4 NCLS=5 HP=24 N=576, M=36864
// External I/O: FLOAT32. Internal GEMM operands: bf16 in workspace.

// ---------------- workspace layout (bytes) ----------------
#define WS_XLOG   ((size_t)0)            // bf16 28311552 el (k_blur -> k_patch)
#define WS_TOKRAW ((size_t)56623104)     // f32 3538944 el (k_patch -> k_ln<true>)
#define WS_VIS    ((size_t)70778880)     // f32 36864     [permanent]
#define WS_WGT    ((size_t)70926336)     // bf16 96*96
#define WS_WIT    ((size_t)70944768)     // bf16 192*96
#define WS_WXT    ((size_t)70981632)     // bf16 128*96
#define WS_WOT    ((size_t)71006208)     // bf16 96*96
#define WS_AMAT   ((size_t)71024640)     // f32 96*16
#define WS_WPE    ((size_t)71030784)     // bf16 96*768
#define WS_CW     ((size_t)71178240)     // f32 3*96 (cw0,cw1,cw2) -> end 71179392
// Phase B (inside dead xlog/tokraw region):
#define WS_TOK    ((size_t)0)            // f32 3538944 (residual stream)
#define WS_GATE   ((size_t)14155776)     // bf16 3538944
#define WS_DNB    ((size_t)21233664)     // bf16 (alias XSB; dnb dead before rep loop writes xsb)
#define WS_XSB    ((size_t)21233664)     // bf16 3538944
#define WS_Y2     ((size_t)28311552)     // bf16 3538944
#define WS_XIN    ((size_t)35389440)     // bf16 3538944
#define WS_ZSV    ((size_t)42467328)     // bf16 3538944
#define WS_DT     ((size_t)49545216)     // bf16 3538944 -> end 56623104
#define WS_BC     ((size_t)56623104)     // bf16 36864*32 -> end 58982400 (dead tokraw)

// ---------------- prep: bf16-ify weights (transposed), W_dt fold, A matrix, conv split ----
#define PREP_STRIDE (128*256)
__global__ __launch_bounds__(256) void k_prep(
    const float* __restrict__ Wgate, const float* __restrict__ Win,
    const float* __restrict__ Wxproj, const float* __restrict__ Wdt,
    const float* __restrict__ Wout, const float* __restrict__ Alog,
    const float* __restrict__ Wpe, const float* __restrict__ convw,
    unsigned short* __restrict__ WgT, unsigned short* __restrict__ WiT,
    unsigned short* __restrict__ WxT, unsigned short* __restrict__ WoT,
    float* __restrict__ Amat, unsigned short* __restrict__ WpeB,
    float* __restrict__ cwsplit)
{
  int gtid = blockIdx.x*256 + threadIdx.x;
  for (int i = gtid; i < 9216; i += PREP_STRIDE){
    int n = i/96, k = i - n*96;
    WgT[n*96+k] = f2b(Wgate[k*96+n]);
    WoT[n*96+k] = f2b(Wout[k*96+n]);
  }
  for (int i = gtid; i < 18432; i += PREP_STRIDE){
    int n = i/96, k = i - n*96;
    WiT[n*96+k] = f2b(Win[k*192+n]);
  }
  for (int i = gtid; i < 12288; i += PREP_STRIDE){
    int n = i/96, k = i - n*96;
    if (n < 96){
      float s = 0.f;
      for (int r = 0; r < 6; ++r) s += Wxproj[k*38+r] * Wdt[r*96+n];
      WxT[n*96+k] = f2b(s);
    } else {
      WxT[n*96+k] = f2b(Wxproj[k*38 + 6 + (n-96)]);
    }
  }
  for (int i = gtid; i < 1536; i += PREP_STRIDE) Amat[i] = -__expf(Alog[i]);
  for (int i = gtid; i < 73728; i += PREP_STRIDE) WpeB[i] = f2b(Wpe[i]);
  for (int i = gtid; i < 96; i += PREP_STRIDE){
    cwsplit[i]       = convw[i*3+0];
    cwsplit[96+i]    = convw[i*3+1];
    cwsplit[192+i]   = convw[i*3+2];
  }
}

// ---------------- K1: 5x5 box blur + log1p diff -> xlog (bf16) ----------------
// bf16 raw-pixel LDS (40.4 KB total -> 4 blocks/CU; was 55.8 KB -> 2).
__global__ __launch_bounds__(256) void k_blur(const float* __restrict__ x,
                                              unsigned short* __restrict__ xlog)
{
  __shared__ unsigned short xt[20*384];  // raw rows y0-2..y0+17, bf16
  __shared__ float vt[16*392];           // vertical 5-sums, padded 4 each side
  int bid = blockIdx.x;                  // 64*3*24
  int tile = bid % 24; int bc = bid / 24; int c = bc % 3; int b = bc / 3;
  const float* xin = x + (size_t)(b*3 + c) * 147456;
  unsigned short* xout = xlog + (size_t)(b*3 + c) * 147456;
  int y0 = tile * 16;
  int tid = threadIdx.x;

  // phase 1: stage 20 rows as bf16 (1920 float4 units)
  #pragma unroll
  for (int k = 0; k < 8; ++k){
    int idx = tid + k*256;
    if (idx < 1920){
      int r = idx / 96; int c4 = idx - r*96;
      int gy = y0 - 2 + r;
      float4 v = make_float4(0.f,0.f,0.f,0.f);
      if (gy >= 0 && gy < 384) v = *(const float4*)(xin + gy*384 + c4*4);
      ushort4 o; o.x=f2b(v.x); o.y=f2b(v.y); o.z=f2b(v.z); o.w=f2b(v.w);
      *(ushort4*)(xt + r*384 + c4*4) = o;
    }
  }
  if (tid < 128){
    int r = tid >> 3; int j = tid & 7;
    vt[r*392 + ((j < 4) ? j : (384 + j))] = 0.f;
  }
  __syncthreads();

  // phase 2: vertical 5-sums, 768 8-col units (3/thread)
  #pragma unroll
  for (int k = 0; k < 3; ++k){
    int unit = tid + k*256;
    int r = unit / 48; int c8 = unit - r*48;
    const unsigned short* base = xt + r*384 + c8*8;
    float acc[8]; float t[8];
    uint4 u0 = *(const uint4*)(base);
    unpack8(u0, acc);
    #pragma unroll
    for (int i = 1; i < 5; ++i){
      uint4 u = *(const uint4*)(base + i*384);
      unpack8(u, t);
      #pragma unroll
      for (int j = 0; j < 8; ++j) acc[j] += t[j];
    }
    float* vrow = vt + r*392 + 4 + c8*8;
    *(float4*)(vrow)   = make_float4(acc[0],acc[1],acc[2],acc[3]);
    *(float4*)(vrow+4) = make_float4(acc[4],acc[5],acc[6],acc[7]);
  }
  __syncthreads();

  // phase 3: horizontal 5-sums + log-diff + bf16 store (1536 4-col units, 6/thread)
  #pragma unroll
  for (int k = 0; k < 6; ++k){
    int unit = tid + k*256;
    int r = unit / 96; int c4 = unit - r*96;
    int base = r*392 + 4 + c4*4;
    float f[12];
    *(float4*)(f)   = *(const float4*)(vt + base - 4);
    *(float4*)(f+4) = *(const float4*)(vt + base);
    *(float4*)(f+8) = *(const float4*)(vt + base + 4);
    ushort4 xr = *(const ushort4*)(xt + (r+2)*384 + c4*4);
    const unsigned short* xrp = &xr.x;
    ushort4 o;
    unsigned short* op = &o.x;
    #pragma unroll
    for (int j = 0; j < 4; ++j){
      float s = f[2+j] + f[3+j] + f[4+j] + f[5+j] + f[6+j];
      float L = fmaxf(s * 0.04f, 0.f);
      float xv = fmaxf(b2f(xrp[j]), 0.f);
      op[j] = f2b(__logf(1.f + xv) - __logf(1.f + L));
    }
    *(ushort4*)(xout + (y0+r)*384 + c4*4) = o;
  }
}

// ---------------- K2: patch embed (MFMA, im2col-free) -> tokens_raw f32 ----------------
__global__ __launch_bounds__(256) void k_patch(const unsigned short* __restrict__ xlog,
    const unsigned short* __restrict__ WpeB, const float* __restrict__ bpe,
    float* __restrict__ tokraw)
{
  int wid = threadIdx.x >> 6, lane = threadIdx.x & 63;
  int m0 = (blockIdx.x*4 + wid)*32;
  int l15 = lane & 15, q = lane >> 4;
  int ma0 = m0 + l15, ma1 = ma0 + 16;
  int b0 = ma0/576; int r0 = ma0 - b0*576; int hp0 = r0/24; int wp0 = r0 - hp0*24;
  int b1 = ma1/576; int r1 = ma1 - b1*576; int hp1 = r1/24; int wp1 = r1 - hp1*24;
  size_t base0 = (size_t)b0*442368 + (size_t)hp0*6144 + (size_t)wp0*16;
  size_t base1 = (size_t)b1*442368 + (size_t)hp1*6144 + (size_t)wp1*16;
  f4v acc[2][6];
  #pragma unroll
  for (int i=0;i<2;++i)
    #pragma unroll
    for (int j=0;j<6;++j)
      #pragma unroll
      for (int r=0;r<4;++r) acc[i][j][r] = 0.f;
  for (int ks = 0; ks < 24; ++ks){
    int k0 = ks*32 + q*8;
    int c  = k0 >> 8;
    int ph = (k0 >> 4) & 15;
    int pw = k0 & 15;
    size_t off = (size_t)c*147456 + (size_t)ph*384 + pw;
    bf8v a0 = *(const bf8v*)(xlog + base0 + off);
    bf8v a1 = *(const bf8v*)(xlog + base1 + off);
    #pragma unroll
    for (int nf = 0; nf < 6; ++nf){
      bf8v bb = *(const bf8v*)(WpeB + (size_t)(nf*16 + l15)*768 + k0);
      acc[0][nf] = __builtin_amdgcn_mfma_f32_16x16x32_bf16(a0, bb, acc[0][nf], 0, 0, 0);
      acc[1][nf] = __builtin_amdgcn_mfma_f32_16x16x32_bf16(a1, bb, acc[1][nf], 0, 0, 0);
    }
  }
  #pragma unroll
  for (int mf=0; mf<2; ++mf)
    #pragma unroll
    for (int nf=0; nf<6; ++nf)
      #pragma unroll
      for (int r=0; r<4; ++r){
        int m = m0 + mf*16 + q*4 + r;
        int n = nf*16 + l15;
        tokraw[(size_t)m*96 + n] = acc[mf][nf][r] + bpe[n];
      }
}

// ---------------- LayerNorm + vis (pre-loop only) ----------------
__global__ __launch_bounds__(256) void k_ln_vis(const float* __restrict__ in,
    const float* __restrict__ g, const float* __restrict__ bta,
    const float* __restrict__ Wvis, const float* __restrict__ bvis,
    float* __restrict__ outf, unsigned short* __restrict__ outb, float* __restrict__ vis)
{
  __shared__ float S[128*97];
  __shared__ float mu[128];
  __shared__ float rs[128];
  size_t base = (size_t)blockIdx.x * 12288;
  const float4* p = (const float4*)(in + base);
  for (int i = threadIdx.x; i < 3072; i += 256){
    float4 v = p[i];
    int e = i*4; int tok = e/96; int k = e - tok*96;
    float* dst = &S[tok*97 + k];
    dst[0]=v.x; dst[1]=v.y; dst[2]=v.z; dst[3]=v.w;
  }
  __syncthreads();
  if (threadIdx.x < 128){
    int tok = threadIdx.x;
    float sum=0.f, sq=0.f, vd=0.f;
    for (int k = 0; k < 96; ++k){
      float xv = S[tok*97+k];
      sum += xv; sq += xv*xv;
      vd += xv * Wvis[k];
    }
    float m = sum * (1.f/96.f);
    float var = sq * (1.f/96.f) - m*m;
    mu[tok] = m;
    rs[tok] = rsqrtf(fmaxf(var, 0.f) + 1e-5f);
    vis[(size_t)blockIdx.x*128 + tok] = sigf(vd + bvis[0]);
  }
  __syncthreads();
  for (int i = threadIdx.x; i < 12288; i += 256){
    int tok = i/96; int k = i - tok*96;
    float val = (S[tok*97+k] - mu[tok]) * rs[tok] * g[k] + bta[k];
    outf[base + i] = val;
    outb[base + i] = f2b(val);
  }
}

// ---------------- generic token GEMM: (36864 x 96) bf16 @ BT(NO x 96) bf16 ----------------
template<int NF, class Epi>
__global__ __launch_bounds__(256) void tokgemm96(const unsigned short* __restrict__ A,
    const unsigned short* __restrict__ BT, Epi epi)
{
  int wid = threadIdx.x >> 6, lane = threadIdx.x & 63;
  int m0 = (blockIdx.x*4 + wid)*32;
  int l15 = lane & 15, q = lane >> 4;
  f4v acc[2][NF];
  #pragma unroll
  for (int i=0;i<2;++i)
    #pragma unroll
    for (int j=0;j<NF;++j)
      #pragma unroll
      for (int r=0;r<4;++r) acc[i][j][r] = 0.f;
  const bf8v* a0p = (const bf8v*)(A) + (size_t)(m0 + l15)*12 + q;
  const bf8v* a1p = a0p + 192;
  const bf8v* bp  = (const bf8v*)(BT) + (size_t)l15*12 + q;
  #pragma unroll
  for (int ks = 0; ks < 3; ++ks){
    bf8v a0 = a0p[ks*4];
    bf8v a1 = a1p[ks*4];
    #pragma unroll
    for (int nf = 0; nf < NF; ++nf){
      bf8v bb = bp[nf*192 + ks*4];
      acc[0][nf] = __builtin_amdgcn_mfma_f32_16x16x32_bf16(a0, bb, acc[0][nf], 0, 0, 0);
      acc[1][nf] = __builtin_amdgcn_mfma_f32_16x16x32_bf16(a1, bb, acc[1][nf], 0, 0, 0);
    }
  }
  #pragma unroll
  for (int mf=0; mf<2; ++mf)
    #pragma unroll
    for (int nf=0; nf<NF; ++nf)
      #pragma unroll
      for (int r=0; r<4; ++r)
        epi(m0 + mf*16 + q*4 + r, nf*16 + l15, acc[mf][nf][r]);
}

struct GateEpi {
  const float* bg; unsigned short* gate;
  __device__ void operator()(int m, int n, float v) const {
    gate[(size_t)m*96 + n] = f2b(sigf(v + bg[n]));
  }
};
struct WoutEpi {
  const unsigned short* gate; float* tokens;
  __device__ void operator()(int m, int n, float v) const {
    size_t i = (size_t)m*96 + n;
    tokens[i] = tokens[i] + v * b2f(gate[i]);
  }
};

// ---------------- fused LN + W_in GEMM (replaces k_ln<false> + tokgemm<12,WinEpi>) -------
__global__ __launch_bounds__(256) void k_lnwin(const float* __restrict__ tokp,
    const float* __restrict__ lng, const float* __restrict__ lnb,
    const unsigned short* __restrict__ BT, const float* __restrict__ vis,
    unsigned short* __restrict__ xin, unsigned short* __restrict__ zsv)
{
  int wid = threadIdx.x >> 6, lane = threadIdx.x & 63;
  int m0 = (blockIdx.x*4 + wid)*32;
  int l15 = lane & 15, q = lane >> 4;
  int ma0 = m0 + l15, ma1 = ma0 + 16;
  float a0v[24], a1v[24];
  float s0=0.f, w0=0.f, s1=0.f, w1=0.f;
  #pragma unroll
  for (int ks = 0; ks < 3; ++ks){
    int k0 = ks*32 + q*8;
    #pragma unroll
    for (int h = 0; h < 2; ++h){
      float4 va = *(const float4*)(tokp + (size_t)ma0*96 + k0 + h*4);
      float4 vb = *(const float4*)(tokp + (size_t)ma1*96 + k0 + h*4);
      int o = ks*8 + h*4;
      a0v[o+0]=va.x; a0v[o+1]=va.y; a0v[o+2]=va.z; a0v[o+3]=va.w;
      a1v[o+0]=vb.x; a1v[o+1]=vb.y; a1v[o+2]=vb.z; a1v[o+3]=vb.w;
      s0 += (va.x+va.y)+(va.z+va.w);
      w0 += (va.x*va.x+va.y*va.y)+(va.z*va.z+va.w*va.w);
      s1 += (vb.x+vb.y)+(vb.z+vb.w);
      w1 += (vb.x*vb.x+vb.y*vb.y)+(vb.z*vb.z+vb.w*vb.w);
    }
  }
  s0 += __shfl_xor(s0, 16); s0 += __shfl_xor(s0, 32);
  w0 += __shfl_xor(w0, 16); w0 += __shfl_xor(w0, 32);
  s1 += __shfl_xor(s1, 16); s1 += __shfl_xor(s1, 32);
  w1 += __shfl_xor(w1, 16); w1 += __shfl_xor(w1, 32);
  float mu0 = s0*(1.f/96.f);
  float rs0 = rsqrtf(fmaxf(w0*(1.f/96.f)-mu0*mu0, 0.f) + 1e-5f);
  float mu1 = s1*(1.f/96.f);
  float rs1 = rsqrtf(fmaxf(w1*(1.f/96.f)-mu1*mu1, 0.f) + 1e-5f);

  bf8v fa0[3], fa1[3];
  #pragma unroll
  for (int ks = 0; ks < 3; ++ks){
    int k0 = ks*32 + q*8;
    float gv[8], bv[8];
    *(float4*)(gv)   = *(const float4*)(lng + k0);
    *(float4*)(gv+4) = *(const float4*)(lng + k0 + 4);
    *(float4*)(bv)   = *(const float4*)(lnb + k0);
    *(float4*)(bv+4) = *(const float4*)(lnb + k0 + 4);
    float v0[8], v1[8];
    #pragma unroll
    for (int j = 0; j < 8; ++j){
      v0[j] = (a0v[ks*8+j]-mu0)*rs0*gv[j] + bv[j];
      v1[j] = (a1v[ks*8+j]-mu1)*rs1*gv[j] + bv[j];
    }
    FragU U0, U1; U0.u = pack8(v0); U1.u = pack8(v1);
    fa0[ks] = U0.v; fa1[ks] = U1.v;
  }

  f4v acc[2][12];
  #pragma unroll
  for (int i=0;i<2;++i)
    #pragma unroll
    for (int j=0;j<12;++j)
      #pragma unroll
      for (int r=0;r<4;++r) acc[i][j][r] = 0.f;
  const bf8v* bp = (const bf8v*)(BT) + (size_t)l15*12 + q;
  #pragma unroll
  for (int ks = 0; ks < 3; ++ks){
    #pragma unroll
    for (int nf = 0; nf < 12; ++nf){
      bf8v bb = bp[nf*192 + ks*4];
      acc[0][nf] = __builtin_amdgcn_mfma_f32_16x16x32_bf16(fa0[ks], bb, acc[0][nf], 0, 0, 0);
      acc[1][nf] = __builtin_amdgcn_mfma_f32_16x16x32_bf16(fa1[ks], bb, acc[1][nf], 0, 0, 0);
    }
  }
  #pragma unroll
  for (int mf=0; mf<2; ++mf)
    #pragma unroll
    for (int nf=0; nf<12; ++nf)
      #pragma unroll
      for (int r=0; r<4; ++r){
        int m = m0 + mf*16 + q*4 + r;
        int n = nf*16 + l15;
        float v = acc[mf][nf][r];
        if (n < 96) xin[(size_t)m*96 + n] = f2b(v);
        else {
          float s = v * sigf(v);
          zsv[(size_t)m*96 + (n-96)] = f2b(s * vis[m]);
        }
      }
}

// ---------------- fused causal dconv+silu + xproj GEMM (replaces k_conv + tokgemm<8>) ----
__global__ __launch_bounds__(256) void k_convxp(const unsigned short* __restrict__ xinb,
    const float* __restrict__ cwsplit, const unsigned short* __restrict__ BT,
    const float* __restrict__ bdt, unsigned short* __restrict__ xsb,
    unsigned short* __restrict__ dt, unsigned short* __restrict__ bc)
{
  int wid = threadIdx.x >> 6, lane = threadIdx.x & 63;
  int m0 = (blockIdx.x*4 + wid)*32;
  int l15 = lane & 15, q = lane >> 4;
  int ma0 = m0 + l15, ma1 = ma0 + 16;
  int t0 = ma0 % 576;     // t(ma1) >= 16 always (m0 mult of 32, 576 mult of 32)
  const float* cw0 = cwsplit;        // conv_w[d][0]
  const float* cw1 = cwsplit + 96;   // conv_w[d][1]
  const float* cw2 = cwsplit + 192;  // conv_w[d][2]

  bf8v fa0[3], fa1[3];
  uint4 z4 = make_uint4(0,0,0,0);
  #pragma unroll
  for (int ks = 0; ks < 3; ++ks){
    int k0 = ks*32 + q*8;
    const unsigned short* r0p = xinb + (size_t)ma0*96 + k0;
    const unsigned short* r1p = xinb + (size_t)ma1*96 + k0;
    uint4 c0u  = *(const uint4*)(r0p);
    uint4 p10u = (t0 >= 1) ? *(const uint4*)(r0p - 96)  : z4;
    uint4 p20u = (t0 >= 2) ? *(const uint4*)(r0p - 192) : z4;
    uint4 c1u  = *(const uint4*)(r1p);
    uint4 p11u = *(const uint4*)(r1p - 96);
    uint4 p21u = *(const uint4*)(r1p - 192);
    float fc0[8], fp10[8], fp20[8], fc1[8], fp11[8], fp21[8];
    unpack8(c0u, fc0); unpack8(p10u, fp10); unpack8(p20u, fp20);
    unpack8(c1u, fc1); unpack8(p11u, fp11); unpack8(p21u, fp21);
    float w0v[8], w1v[8], w2v[8];
    *(float4*)(w0v)   = *(const float4*)(cw0 + k0);
    *(float4*)(w0v+4) = *(const float4*)(cw0 + k0 + 4);
    *(float4*)(w1v)   = *(const float4*)(cw1 + k0);
    *(float4*)(w1v+4) = *(const float4*)(cw1 + k0 + 4);
    *(float4*)(w2v)   = *(const float4*)(cw2 + k0);
    *(float4*)(w2v+4) = *(const float4*)(cw2 + k0 + 4);
    float xs0[8], xs1[8];
    #pragma unroll
    for (int j = 0; j < 8; ++j){
      float v0 = w2v[j]*fc0[j] + w1v[j]*fp10[j] + w0v[j]*fp20[j];
      float v1 = w2v[j]*fc1[j] + w1v[j]*fp11[j] + w0v[j]*fp21[j];
      xs0[j] = v0 * sigf(v0);
      xs1[j] = v1 * sigf(v1);
    }
    FragU U0, U1; U0.u = pack8(xs0); U1.u = pack8(xs1);
    fa0[ks] = U0.v; fa1[ks] = U1.v;
    *(uint4*)(xsb + (size_t)ma0*96 + k0) = U0.u;
    *(uint4*)(xsb + (size_t)ma1*96 + k0) = U1.u;
  }

  f4v acc[2][8];
  #pragma unroll
  for (int i=0;i<2;++i)
    #pragma unroll
    for (int j=0;j<8;++j)
      #pragma unroll
      for (int r=0;r<4;++r) acc[i][j][r] = 0.f;
  const bf8v* bp = (const bf8v*)(BT) + (size_t)l15*12 + q;
  #pragma unroll
  for (int ks = 0; ks < 3; ++ks){
    #pragma unroll
    for (int nf = 0; nf < 8; ++nf){
      bf8v bb = bp[nf*192 + ks*4];
      acc[0][nf] = __builtin_amdgcn_mfma_f32_16x16x32_bf16(fa0[ks], bb, acc[0][nf], 0, 0, 0);
      acc[1][nf] = __builtin_amdgcn_mfma_f32_16x16x32_bf16(fa1[ks], bb, acc[1][nf], 0, 0, 0);
    }
  }
  #pragma unroll
  for (int mf=0; mf<2; ++mf)
    #pragma unroll
    for (int nf=0; nf<8; ++nf)
      #pragma unroll
      for (int r=0; r<4; ++r){
        int m = m0 + mf*16 + q*4 + r;
        int n = nf*16 + l15;
        float v = acc[mf][nf][r];
        if (n < 96){
          float xx = v + bdt[n];
          float sp = (xx > 20.f) ? xx : __logf(1.f + __expf(xx));
          dt[(size_t)m*96 + n] = f2b(sp);
        } else {
          bc[(size_t)m*32 + (n-96)] = f2b(v);
        }
      }
}

// ---------------- selective scan: chunked 2-pass with in-LDS combine ----------------
__global__ __launch_bounds__(384) void k_scan(const unsigned short* __restrict__ dt,
    const unsigned short* __restrict__ xsb, const unsigned short* __restrict__ bc,
    const unsigned short* __restrict__ zsv, const float* __restrict__ Amat,
    const float* __restrict__ Dw, unsigned short* __restrict__ y2)
{
  __shared__ float Ul[24*16*17];
  __shared__ float Sl[24*16];
  int b = blockIdx.x / 6; int dg = blockIdx.x - b*6;
  int tid = threadIdx.x;
  int c = tid >> 4; int dl = tid & 15; int d = dg*16 + dl;
  float As[16];
  #pragma unroll
  for (int s = 0; s < 16; s += 4){
    float4 t4 = *(const float4*)(Amat + d*16 + s);
    As[s]=t4.x; As[s+1]=t4.y; As[s+2]=t4.z; As[s+3]=t4.w;
  }
  float h[16];
  #pragma unroll
  for (int s=0;s<16;++s) h[s]=0.f;
  float sdt = 0.f;
  int tbase = b*576 + c*24;
  for (int i = 0; i < 24; ++i){
    size_t m = (size_t)(tbase + i);
    float dtv = b2f(dt[m*96 + d]);
    float dtx = dtv * b2f(xsb[m*96 + d]);
    const uint4* bp = (const uint4*)(bc + m*32);
    float Bv[16];
    unpack8(bp[0], Bv); unpack8(bp[1], Bv+8);
    sdt += dtv;
    #pragma unroll
    for (int s=0;s<16;++s) h[s] = __expf(As[s]*dtv)*h[s] + dtx*Bv[s];
  }
  {
    int base = (c*16 + dl)*17;
    #pragma unroll
    for (int s=0;s<16;++s) Ul[base + s] = h[s];
    Sl[c*16 + dl] = sdt;
  }
  __syncthreads();
  if (tid < 256){
    int dl2 = tid >> 4, s2 = tid & 15;
    float A2 = Amat[(dg*16 + dl2)*16 + s2];
    float hh = 0.f;
    for (int cc = 0; cc < 24; ++cc){
      float u = Ul[(cc*16 + dl2)*17 + s2];
      float ss = Sl[cc*16 + dl2];
      hh = __expf(A2*ss)*hh + u;
      Ul[(cc*16 + dl2)*17 + s2] = hh;
    }
  }
  __syncthreads();
  if (c == 0){
    #pragma unroll
    for (int s=0;s<16;++s) h[s] = 0.f;
  } else {
    int base = ((c-1)*16 + dl)*17;
    #pragma unroll
    for (int s=0;s<16;++s) h[s] = Ul[base + s];
  }
  float Dd = Dw[d];
  for (int i = 0; i < 24; ++i){
    size_t m = (size_t)(tbase + i);
    float dtv = b2f(dt[m*96 + d]);
    float xv = b2f(xsb[m*96 + d]);
    float dtx = dtv * xv;
    const uint4* bp = (const uint4*)(bc + m*32);
    float Bv[16], Cv[16];
    unpack8(bp[0], Bv); unpack8(bp[1], Bv+8);
    unpack8(bp[2], Cv); unpack8(bp[3], Cv+8);
    float p0=0.f,p1=0.f,p2=0.f,p3=0.f;
    #pragma unroll
    for (int s=0;s<16;s+=4){
      h[s+0] = __expf(As[s+0]*dtv)*h[s+0] + dtx*Bv[s+0]; p0 += h[s+0]*Cv[s+0];
      h[s+1] = __expf(As[s+1]*dtv)*h[s+1] + dtx*Bv[s+1]; p1 += h[s+1]*Cv[s+1];
      h[s+2] = __expf(As[s+2]*dtv)*h[s+2] + dtx*Bv[s+2]; p2 += h[s+2]*Cv[s+2];
      h[s+3] = __expf(As[s+3]*dtv)*h[s+3] + dtx*Bv[s+3]; p3 += h[s+3]*Cv[s+3];
    }
    float y = (p0+p1) + (p2+p3);
    float yv = (y + Dd*xv) * b2f(zsv[m*96 + d]);
    y2[m*96 + d] = f2b(yv);
  }
}

// ---------------- head: depthwise 3x3 + BN + silu + linear heads ----------------
__global__ __launch_bounds__(256) void k_head(const float* __restrict__ tokens,
    const float* __restrict__ hdw, const float* __restrict__ bng,
    const float* __restrict__ bnb, const float* __restrict__ bnm,
    const float* __restrict__ bnv, const float* __restrict__ Wheat,
    const float* __restrict__ bheat, const float* __restrict__ Woff,
    const float* __restrict__ boff, const float* __restrict__ Wsize,
    const float* __restrict__ bsize, float* __restrict__ out)
{
  __shared__ float ft[3*2304];
  __shared__ float act[2304];
  int b = blockIdx.x / 24; int h = blockIdx.x - b*24;
  for (int i = threadIdx.x; i < 3*2304; i += 256){
    int rr = i / 2304; int j = i - rr*2304;
    int hh = h + rr - 1;
    float v = 0.f;
    if (hh >= 0 && hh < 24) v = tokens[((size_t)b*576 + hh*24)*96 + j];
    ft[rr*2304 + j] = v;
  }
  __syncthreads();
  for (int i = threadIdx.x; i < 2304; i += 256){
    int w = i / 96; int cc = i - w*96;
    float g = 0.f;
    #pragma unroll
    for (int dh = 0; dh < 3; ++dh){
      #pragma unroll
      for (int dw = 0; dw < 3; ++dw){
        int ww = w + dw - 1;
        if (ww >= 0 && ww < 24) g += ft[dh*2304 + ww*96 + cc] * hdw[cc*9 + dh*3 + dw];
      }
    }
    float gn = (g - bnm[cc]) * rsqrtf(bnv[cc] + 1e-5f);
    float a = gn * bng[cc] + bnb[cc];
    act[i] = a * sigf(a);
  }
  __syncthreads();
  int tid = threadIdx.x;
  if (tid < 120){
    int o = tid / 24; int w = tid - o*24;
    float s = 0.f;
    for (int cc = 0; cc < 96; ++cc) s += act[w*96 + cc] * Wheat[o*96 + cc];
    s += bheat[o];
    out[(size_t)b*2880 + o*576 + h*24 + w] = s;
  } else if (tid >= 128 && tid < 224){
    int idx = tid - 128; int o2 = idx / 24; int w = idx - o2*24;
    const float* W = (o2 < 2) ? Woff : Wsize;
    int o = o2 & 1;
    float s = 0.f;
    for (int cc = 0; cc < 96; ++cc) s += ft[2304 + w*96 + cc] * W[o*96 + cc];
    s += ((o2 < 2) ? boff : bsize)[o];
    size_t baseo = (o2 < 2) ? (size_t)184320 : (size_t)258048;
    out[baseo + (size_t)b*1152 + o*576 + h*24 + w] = s;
  }
}

// ---------------- host ----------------
extern "C" void kernel_launch(void* const* d_in, const int* in_sizes, int n_in,
                              void* d_out, int out_size, void* d_ws, size_t ws_size,
                              hipStream_t stream)
{
  (void)in_sizes; (void)n_in; (void)out_size; (void)ws_size;
  const float* x      = (const float*)d_in[0];
  const float* Wpe    = (const float*)d_in[1];
  const float* bpe    = (const float*)d_in[2];
  const float* Wvis   = (const float*)d_in[3];
  const float* bvis   = (const float*)d_in[4];
  const float* dng    = (const float*)d_in[5];
  const float* dnb    = (const float*)d_in[6];
  const float* Wgate  = (const float*)d_in[7];
  const float* bgate  = (const float*)d_in[8];
  const float* lng    = (const float*)d_in[9];
  const float* lnb    = (const float*)d_in[10];
  const float* Win    = (const float*)d_in[11];
  const float* convw  = (const float*)d_in[12];
  const float* Wxproj = (const float*)d_in[13];
  const float* Wdt    = (const float*)d_in[14];
  const float* bdt    = (const float*)d_in[15];
  const float* Alog   = (const float*)d_in[16];
  const float* Dw     = (const float*)d_in[17];
  const float* Wout   = (const float*)d_in[18];
  const float* hddw   = (const float*)d_in[19];
  const float* bng    = (const float*)d_in[20];
  const float* bnb    = (const float*)d_in[21];
  const float* bnm    = (const float*)d_in[22];
  const float* bnv    = (const float*)d_in[23];
  const float* Wheat  = (const float*)d_in[24];
  const float* bheat  = (const float*)d_in[25];
  const float* Woff   = (const float*)d_in[26];
  const float* boff   = (const float*)d_in[27];
  const float* Wsize  = (const float*)d_in[28];
  const float* bsize  = (const float*)d_in[29];
  float* out = (float*)d_out;

  char* ws = (char*)d_ws;
  unsigned short* xlog  = (unsigned short*)(ws + WS_XLOG);
  float*          tokraw= (float*)(ws + WS_TOKRAW);
  float*          vis   = (float*)(ws + WS_VIS);
  unsigned short* WgT   = (unsigned short*)(ws + WS_WGT);
  unsigned short* WiT   = (unsigned short*)(ws + WS_WIT);
  unsigned short* WxT   = (unsigned short*)(ws + WS_WXT);
  unsigned short* WoT   = (unsigned short*)(ws + WS_WOT);
  float*          Amat  = (float*)(ws + WS_AMAT);
  unsigned short* WpeB  = (unsigned short*)(ws + WS_WPE);
  float*          cwsp  = (float*)(ws + WS_CW);
  float*          tok   = (float*)(ws + WS_TOK);
  unsigned short* gate  = (unsigned short*)(ws + WS_GATE);
  unsigned short* dnbf  = (unsigned short*)(ws + WS_DNB);
  unsigned short* xsb   = (unsigned short*)(ws + WS_XSB);
  unsigned short* y2    = (unsigned short*)(ws + WS_Y2);
  unsigned short* xinb  = (unsigned short*)(ws + WS_XIN);
  unsigned short* zsvb  = (unsigned short*)(ws + WS_ZSV);
  unsigned short* dtb   = (unsigned short*)(ws + WS_DT);
  unsigned short* bcb   = (unsigned short*)(ws + WS_BC);

  k_prep<<<128, 256, 0, stream>>>(Wgate, Win, Wxproj, Wdt, Wout, Alog, Wpe, convw,
                                  WgT, WiT, WxT, WoT, Amat, WpeB, cwsp);
  k_blur<<<4608, 256, 0, stream>>>(x, xlog);
  k_patch<<<288, 256, 0, stream>>>(xlog, WpeB, bpe, tokraw);
  k_ln_vis<<<288, 256, 0, stream>>>(tokraw, dng, dnb, Wvis, bvis, tok, dnbf, vis);
  tokgemm96<6, GateEpi><<<288, 256, 0, stream>>>(dnbf, WgT, GateEpi{bgate, gate});

  for (int rep = 0; rep < 4; ++rep){
    k_lnwin<<<288, 256, 0, stream>>>(tok, lng, lnb, WiT, vis, xinb, zsvb);
    k_convxp<<<288, 256, 0, stream>>>(xinb, cwsp, WxT, bdt, xsb, dtb, bcb);
    k_scan<<<384, 384, 0, stream>>>(dtb, xsb, bcb, zsvb, Amat, Dw, y2);
    tokgemm96<6, WoutEpi><<<288, 256, 0, stream>>>(y2, WoT, WoutEpi{gate, tok});
  }

  k_head<<<1536, 256, 0, stream>>>(tok, hddw, bng, bnb, bnm, bnv,
                                   Wheat, bheat, Woff, boff, Wsize, bsize, out);
}